// Round 1
// baseline (388.605 us; speedup 1.0000x reference)
//
#include <hip/hip_runtime.h>

typedef __attribute__((ext_vector_type(8))) _Float16 h8;
typedef __attribute__((ext_vector_type(4))) _Float16 h4;
typedef __attribute__((ext_vector_type(4))) float f4;

#define MFMA16(a,b,c) __builtin_amdgcn_mfma_f32_16x16x32_f16(a,b,c,0,0,0)

// ---------------- fp32 -> f16 elementwise (vectorized) ----------------
__global__ __launch_bounds__(256) void k_f32_to_f16(const float* __restrict__ in,
                                                    _Float16* __restrict__ out, int n4) {
    int i = blockIdx.x * 256 + threadIdx.x;
    if (i < n4) {
        float4 v = ((const float4*)in)[i];
        h4 h;
        h[0] = (_Float16)v.x; h[1] = (_Float16)v.y;
        h[2] = (_Float16)v.z; h[3] = (_Float16)v.w;
        ((h4*)out)[i] = h;
    }
}

// ---------------- fp32 (K,N) -> f16 (N,K) tiled transpose ----------------
__global__ __launch_bounds__(256) void k_transpose_f16(const float* __restrict__ W,
                                                       _Float16* __restrict__ Wt,
                                                       int K, int N) {
    __shared__ float tile[64 * 68];
    const int k0 = blockIdx.x * 64, n0 = blockIdx.y * 64;
    const int t = threadIdx.x;
    const int tr = t >> 4;        // 0..15
    const int tc = t & 15;        // 0..15
#pragma unroll
    for (int i = 0; i < 4; ++i) {
        int r = tr + i * 16;
        float4 v = *(const float4*)(W + (size_t)(k0 + r) * N + n0 + tc * 4);
        *(float4*)(&tile[r * 68 + tc * 4]) = v;
    }
    __syncthreads();
#pragma unroll
    for (int i = 0; i < 4; ++i) {
        int nl = tr + i * 16;     // local out-row (= original col)
        h4 hv;
#pragma unroll
        for (int j = 0; j < 4; ++j)
            hv[j] = (_Float16)tile[(tc * 4 + j) * 68 + nl];
        *(h4*)(Wt + (size_t)(n0 + nl) * K + k0 + tc * 4) = hv;
    }
}

// ---------------- 128x128 MFMA GEMM: C = A(MxK) * Bt(NxK)^T + bias ----------------
// MODE 0: scatter into Q/K/V f16 buffers laid out (B,H,T,64).  MODE 1: fp32 out.
template <int MODE>
__global__ __launch_bounds__(256) void k_gemm(const _Float16* __restrict__ A,
                                              const _Float16* __restrict__ Bt,
                                              const float* __restrict__ bias,
                                              _Float16* __restrict__ oQ,
                                              _Float16* __restrict__ oK,
                                              _Float16* __restrict__ oV,
                                              float* __restrict__ oF,
                                              int M, int N, int K) {
    // +8 pad: row stride 80B -> 16-lane frag reads land on 8 banks (2-way, free)
    __shared__ _Float16 As[128 * 40];
    __shared__ _Float16 Bs[128 * 40];
    const int tid = threadIdx.x;
    const int lane = tid & 63, wv = tid >> 6;
    const int wm = wv >> 1, wn = wv & 1;
    const int l15 = lane & 15, l4 = lane >> 4;
    const int bm = blockIdx.x * 128, bn = blockIdx.y * 128;
    const int lr = tid >> 2, lc = (tid & 3) * 8;
    f4 acc[4][4] = {};
    const _Float16* Ap = A + (size_t)(bm + lr) * K + lc;
    const _Float16* Bp = Bt + (size_t)(bn + lr) * K + lc;

    for (int k0 = 0; k0 < K; k0 += 32) {
        __syncthreads();
        h8 a0 = *(const h8*)(Ap + k0);
        h8 a1 = *(const h8*)(Ap + (size_t)64 * K + k0);
        h8 b0 = *(const h8*)(Bp + k0);
        h8 b1 = *(const h8*)(Bp + (size_t)64 * K + k0);
        *(h8*)(&As[lr * 40 + lc]) = a0;
        *(h8*)(&As[(lr + 64) * 40 + lc]) = a1;
        *(h8*)(&Bs[lr * 40 + lc]) = b0;
        *(h8*)(&Bs[(lr + 64) * 40 + lc]) = b1;
        __syncthreads();
        h8 af[4], bf[4];
#pragma unroll
        for (int i = 0; i < 4; ++i)
            af[i] = *(const h8*)(&As[(wm * 64 + i * 16 + l15) * 40 + l4 * 8]);
#pragma unroll
        for (int i = 0; i < 4; ++i)
            bf[i] = *(const h8*)(&Bs[(wn * 64 + i * 16 + l15) * 40 + l4 * 8]);
#pragma unroll
        for (int mi = 0; mi < 4; ++mi)
#pragma unroll
            for (int ni = 0; ni < 4; ++ni)
                acc[mi][ni] = MFMA16(af[mi], bf[ni], acc[mi][ni]);
    }

#pragma unroll
    for (int mi = 0; mi < 4; ++mi) {
#pragma unroll
        for (int ni = 0; ni < 4; ++ni) {
            int col = bn + wn * 64 + ni * 16 + l15;
            float bv = bias[col];
            int rb = bm + wm * 64 + mi * 16 + l4 * 4;
            if (MODE == 0) {
                int which = col >> 10, n1 = col & 1023;
                int hh = n1 >> 6, dd = n1 & 63;
                _Float16* dst = which == 0 ? oQ : (which == 1 ? oK : oV);
#pragma unroll
                for (int i = 0; i < 4; ++i) {
                    int row = rb + i;
                    int b = row >> 11, tq = row & 2047;
                    dst[(((size_t)b * 16 + hh) * 2048 + tq) * 64 + dd] =
                        (_Float16)(acc[mi][ni][i] + bv);
                }
            } else {
#pragma unroll
                for (int i = 0; i < 4; ++i)
                    oF[(size_t)(rb + i) * N + col] = acc[mi][ni][i] + bv;
            }
        }
    }
}

// ---------------- causal flash attention, 64 q-rows/block, KV tile = 64 ----------------
__global__ __launch_bounds__(256) void k_attn(const _Float16* __restrict__ Qh,
                                              const _Float16* __restrict__ Kh,
                                              const _Float16* __restrict__ Vh,
                                              _Float16* __restrict__ Yh) {
    __shared__ _Float16 Ks[64 * 72];          // [key][d], padded
    __shared__ _Float16 Vs[64 * 72];          // [d][key] (transposed), padded
    __shared__ _Float16 Ps[4 * 16 * 72];      // per-wave P tile [16 q][64 key], padded
    const int qb = blockIdx.x & 31;           // T/64 = 32 q-blocks
    const int bh = blockIdx.x >> 5;           // 0..63 = b*16+h
    const int tid = threadIdx.x, lane = tid & 63, w = tid >> 6;
    const int l15 = lane & 15, l4 = lane >> 4;
    const size_t base = (size_t)bh * 2048 * 64;

    const int qrow = qb * 64 + w * 16 + l15;
    h8 qf0 = *(const h8*)(Qh + base + (size_t)qrow * 64 + l4 * 8);
    h8 qf1 = *(const h8*)(Qh + base + (size_t)qrow * 64 + 32 + l4 * 8);

    f4 O[4] = {};
    float mrow[4] = {-1e30f, -1e30f, -1e30f, -1e30f};
    float lrow[4] = {0.f, 0.f, 0.f, 0.f};
    const int tkey = tid >> 2, tcol = (tid & 3) * 8;
    _Float16* Pw = Ps + w * 16 * 72;

    for (int kb = 0; kb <= qb; ++kb) {
        __syncthreads();
        // stage K [64][64] and V transposed [64][64]
        const _Float16* Kg = Kh + base + (size_t)(kb * 64 + tkey) * 64 + tcol;
        const _Float16* Vg = Vh + base + (size_t)(kb * 64 + tkey) * 64 + tcol;
        h8 kv0 = *(const h8*)(Kg);
        h8 kv1 = *(const h8*)(Kg + 32);
        *(h8*)(&Ks[tkey * 72 + tcol]) = kv0;
        *(h8*)(&Ks[tkey * 72 + tcol + 32]) = kv1;
        h8 vv0 = *(const h8*)(Vg);
        h8 vv1 = *(const h8*)(Vg + 32);
#pragma unroll
        for (int j = 0; j < 8; ++j) Vs[(tcol + j) * 72 + tkey] = vv0[j];
#pragma unroll
        for (int j = 0; j < 8; ++j) Vs[(tcol + 32 + j) * 72 + tkey] = vv1[j];
        __syncthreads();

        // QK^T: 4 key sub-tiles of 16
        f4 s[4];
#pragma unroll
        for (int nt = 0; nt < 4; ++nt) {
            h8 b0 = *(const h8*)(&Ks[(nt * 16 + l15) * 72 + l4 * 8]);
            h8 b1 = *(const h8*)(&Ks[(nt * 16 + l15) * 72 + 32 + l4 * 8]);
            f4 c = {};
            c = MFMA16(qf0, b0, c);
            c = MFMA16(qf1, b1, c);
            s[nt] = c;
        }

        // scale + causal mask (only diagonal block) + row max
        const bool diag = (kb == qb);
        float pm[4] = {-1e30f, -1e30f, -1e30f, -1e30f};
#pragma unroll
        for (int nt = 0; nt < 4; ++nt)
#pragma unroll
            for (int i = 0; i < 4; ++i) {
                float v = s[nt][i] * 0.125f;
                if (diag) {
                    int key = nt * 16 + l15;
                    int row = w * 16 + l4 * 4 + i;
                    if (key > row) v = -1e30f;
                }
                s[nt][i] = v;
                pm[i] = fmaxf(pm[i], v);
            }
#pragma unroll
        for (int mm = 1; mm < 16; mm <<= 1)
#pragma unroll
            for (int i = 0; i < 4; ++i) pm[i] = fmaxf(pm[i], __shfl_xor(pm[i], mm));

        float sc[4], rs[4];
#pragma unroll
        for (int i = 0; i < 4; ++i) {
            float mn = fmaxf(mrow[i], pm[i]);
            sc[i] = __expf(mrow[i] - mn);
            mrow[i] = mn;
            rs[i] = 0.f;
        }
#pragma unroll
        for (int nt = 0; nt < 4; ++nt)
#pragma unroll
            for (int i = 0; i < 4; ++i) {
                float p = __expf(s[nt][i] - mrow[i]);
                rs[i] += p;
                Pw[(l4 * 4 + i) * 72 + nt * 16 + l15] = (_Float16)p;
            }
#pragma unroll
        for (int mm = 1; mm < 16; mm <<= 1)
#pragma unroll
            for (int i = 0; i < 4; ++i) rs[i] += __shfl_xor(rs[i], mm);
#pragma unroll
        for (int i = 0; i < 4; ++i) lrow[i] = lrow[i] * sc[i] + rs[i];
#pragma unroll
        for (int dt = 0; dt < 4; ++dt)
#pragma unroll
            for (int i = 0; i < 4; ++i) O[dt][i] *= sc[i];

        // PV: P (16x64) @ V (64x64)
        h8 pf0 = *(const h8*)(&Pw[l15 * 72 + l4 * 8]);
        h8 pf1 = *(const h8*)(&Pw[l15 * 72 + 32 + l4 * 8]);
#pragma unroll
        for (int dt = 0; dt < 4; ++dt) {
            h8 v0 = *(const h8*)(&Vs[(dt * 16 + l15) * 72 + l4 * 8]);
            h8 v1 = *(const h8*)(&Vs[(dt * 16 + l15) * 72 + 32 + l4 * 8]);
            O[dt] = MFMA16(pf0, v0, O[dt]);
            O[dt] = MFMA16(pf1, v1, O[dt]);
        }
    }

    // epilogue: normalize and write Y (B,T,C) f16
    const int b = bh >> 4, h = bh & 15;
#pragma unroll
    for (int i = 0; i < 4; ++i) {
        float inv = 1.0f / lrow[i];
        int q = qb * 64 + w * 16 + l4 * 4 + i;
        _Float16* yp = Yh + ((size_t)(b * 2048 + q)) * 1024 + h * 64;
#pragma unroll
        for (int dt = 0; dt < 4; ++dt)
            yp[dt * 16 + l15] = (_Float16)(O[dt][i] * inv);
    }
}

extern "C" void kernel_launch(void* const* d_in, const int* in_sizes, int n_in,
                              void* d_out, int out_size, void* d_ws, size_t ws_size,
                              hipStream_t stream) {
    const float* x  = (const float*)d_in[0];
    const float* Wa = (const float*)d_in[1];
    const float* ba = (const float*)d_in[2];
    const float* Wp = (const float*)d_in[3];
    const float* bp = (const float*)d_in[4];
    float* out = (float*)d_out;

    _Float16* ws = (_Float16*)d_ws;
    const size_t SZ_X = (size_t)8192 * 1024;
    const size_t SZ_WA = (size_t)3072 * 1024;
    const size_t SZ_WP = (size_t)1024 * 1024;
    const size_t SZ_H = (size_t)64 * 2048 * 64;
    _Float16* xh  = ws;
    _Float16* WaT = xh + SZ_X;
    _Float16* WpT = WaT + SZ_WA;
    _Float16* Qh  = WpT + SZ_WP;
    _Float16* Kh  = Qh + SZ_H;
    _Float16* Vh  = Kh + SZ_H;
    _Float16* Yh  = Vh + SZ_H;

    k_f32_to_f16<<<8192, 256, 0, stream>>>(x, xh, (int)(SZ_X / 4));
    k_transpose_f16<<<dim3(16, 48), 256, 0, stream>>>(Wa, WaT, 1024, 3072);
    k_transpose_f16<<<dim3(16, 16), 256, 0, stream>>>(Wp, WpT, 1024, 1024);
    k_gemm<0><<<dim3(64, 24), 256, 0, stream>>>(xh, WaT, ba, Qh, Kh, Vh, nullptr,
                                                8192, 3072, 1024);
    k_attn<<<2048, 256, 0, stream>>>(Qh, Kh, Vh, Yh);
    k_gemm<1><<<dim3(64, 8), 256, 0, stream>>>(Yh, WpT, bp, nullptr, nullptr, nullptr,
                                               out, 8192, 1024, 1024);
}

// Round 2
// 348.053 us; speedup vs baseline: 1.1165x; 1.1165x over previous
//
#include <hip/hip_runtime.h>

typedef __attribute__((ext_vector_type(8))) _Float16 h8;
typedef __attribute__((ext_vector_type(4))) _Float16 h4;
typedef __attribute__((ext_vector_type(4))) float f4;

#define MFMA16(a,b,c) __builtin_amdgcn_mfma_f32_16x16x32_f16(a,b,c,0,0,0)

// ---------------- fp32 -> f16 elementwise (vectorized) ----------------
__global__ __launch_bounds__(256) void k_f32_to_f16(const float* __restrict__ in,
                                                    _Float16* __restrict__ out, int n4) {
    int i = blockIdx.x * 256 + threadIdx.x;
    if (i < n4) {
        float4 v = ((const float4*)in)[i];
        h4 h;
        h[0] = (_Float16)v.x; h[1] = (_Float16)v.y;
        h[2] = (_Float16)v.z; h[3] = (_Float16)v.w;
        ((h4*)out)[i] = h;
    }
}

// ---------------- fp32 (K,N) -> f16 (N,K) tiled transpose ----------------
__global__ __launch_bounds__(256) void k_transpose_f16(const float* __restrict__ W,
                                                       _Float16* __restrict__ Wt,
                                                       int K, int N) {
    __shared__ float tile[64 * 68];
    const int k0 = blockIdx.x * 64, n0 = blockIdx.y * 64;
    const int t = threadIdx.x;
    const int tr = t >> 4;        // 0..15
    const int tc = t & 15;        // 0..15
#pragma unroll
    for (int i = 0; i < 4; ++i) {
        int r = tr + i * 16;
        float4 v = *(const float4*)(W + (size_t)(k0 + r) * N + n0 + tc * 4);
        *(float4*)(&tile[r * 68 + tc * 4]) = v;
    }
    __syncthreads();
#pragma unroll
    for (int i = 0; i < 4; ++i) {
        int nl = tr + i * 16;     // local out-row (= original col)
        h4 hv;
#pragma unroll
        for (int j = 0; j < 4; ++j)
            hv[j] = (_Float16)tile[(tc * 4 + j) * 68 + nl];
        *(h4*)(Wt + (size_t)(n0 + nl) * K + k0 + tc * 4) = hv;
    }
}

// ---------------- 128x128 MFMA GEMM: C = A(MxK) * Bt(NxK)^T + bias ----------------
// MODE 0: scatter into Q/K (B,H,T,64) and V^T (B,H,64,T) f16 buffers; Q pre-scaled 1/8.
// MODE 1: fp32 out.
template <int MODE>
__global__ __launch_bounds__(256) void k_gemm(const _Float16* __restrict__ A,
                                              const _Float16* __restrict__ Bt,
                                              const float* __restrict__ bias,
                                              _Float16* __restrict__ oQ,
                                              _Float16* __restrict__ oK,
                                              _Float16* __restrict__ oV,
                                              float* __restrict__ oF,
                                              int M, int N, int K) {
    __shared__ _Float16 As[128 * 40];
    __shared__ _Float16 Bs[128 * 40];
    const int tid = threadIdx.x;
    const int lane = tid & 63, wv = tid >> 6;
    const int wm = wv >> 1, wn = wv & 1;
    const int l15 = lane & 15, l4 = lane >> 4;
    const int bm = blockIdx.x * 128, bn = blockIdx.y * 128;
    const int lr = tid >> 2, lc = (tid & 3) * 8;
    f4 acc[4][4] = {};
    const _Float16* Ap = A + (size_t)(bm + lr) * K + lc;
    const _Float16* Bp = Bt + (size_t)(bn + lr) * K + lc;

    for (int k0 = 0; k0 < K; k0 += 32) {
        __syncthreads();
        h8 a0 = *(const h8*)(Ap + k0);
        h8 a1 = *(const h8*)(Ap + (size_t)64 * K + k0);
        h8 b0 = *(const h8*)(Bp + k0);
        h8 b1 = *(const h8*)(Bp + (size_t)64 * K + k0);
        *(h8*)(&As[lr * 40 + lc]) = a0;
        *(h8*)(&As[(lr + 64) * 40 + lc]) = a1;
        *(h8*)(&Bs[lr * 40 + lc]) = b0;
        *(h8*)(&Bs[(lr + 64) * 40 + lc]) = b1;
        __syncthreads();
        h8 af[4], bf[4];
#pragma unroll
        for (int i = 0; i < 4; ++i)
            af[i] = *(const h8*)(&As[(wm * 64 + i * 16 + l15) * 40 + l4 * 8]);
#pragma unroll
        for (int i = 0; i < 4; ++i)
            bf[i] = *(const h8*)(&Bs[(wn * 64 + i * 16 + l15) * 40 + l4 * 8]);
#pragma unroll
        for (int mi = 0; mi < 4; ++mi)
#pragma unroll
            for (int ni = 0; ni < 4; ++ni)
                acc[mi][ni] = MFMA16(af[mi], bf[ni], acc[mi][ni]);
    }

#pragma unroll
    for (int mi = 0; mi < 4; ++mi) {
#pragma unroll
        for (int ni = 0; ni < 4; ++ni) {
            int col = bn + wn * 64 + ni * 16 + l15;
            float bv = bias[col];
            int rb = bm + wm * 64 + mi * 16 + l4 * 4;
            if (MODE == 0) {
                int which = col >> 10, n1 = col & 1023;
                int hh = n1 >> 6, dd = n1 & 63;
                if (which == 2) {
                    // V: write transposed (bh, d, t); rows rb..rb+3 are t-contiguous
                    int b = rb >> 11, tq = rb & 2047;
                    h4 pv;
#pragma unroll
                    for (int i = 0; i < 4; ++i) pv[i] = (_Float16)(acc[mi][ni][i] + bv);
                    *(h4*)(oV + ((size_t)(b * 16 + hh) * 64 + dd) * 2048 + tq) = pv;
                } else {
                    _Float16* dst = which == 0 ? oQ : oK;
                    const float scl = which == 0 ? 0.125f : 1.0f;
#pragma unroll
                    for (int i = 0; i < 4; ++i) {
                        int row = rb + i;
                        int b = row >> 11, tq = row & 2047;
                        dst[(((size_t)b * 16 + hh) * 2048 + tq) * 64 + dd] =
                            (_Float16)((acc[mi][ni][i] + bv) * scl);
                    }
                }
            } else {
#pragma unroll
                for (int i = 0; i < 4; ++i)
                    oF[(size_t)(rb + i) * N + col] = acc[mi][ni][i] + bv;
            }
        }
    }
}

// ---------------- causal flash attention: 128 q-rows/block (4 waves x 32), KV tile 64 ----------------
__global__ __launch_bounds__(256) void k_attn(const _Float16* __restrict__ Qh,
                                              const _Float16* __restrict__ Kh,
                                              const _Float16* __restrict__ Vt,
                                              _Float16* __restrict__ Yh) {
    __shared__ _Float16 Ks[64 * 72];           // [key][d], padded
    __shared__ _Float16 Vs[64 * 72];           // [d][key] (pre-transposed in HBM), padded
    __shared__ _Float16 Ps[4 * 32 * 72];       // per-wave P tile [32 q][64 key], padded
    const int qb = 15 - (blockIdx.x & 15);     // long blocks first
    const int bh = blockIdx.x >> 4;
    const int tid = threadIdx.x, lane = tid & 63, w = tid >> 6;
    const int l15 = lane & 15, l4 = lane >> 4;
    const size_t base = (size_t)bh * 2048 * 64;

    const int q0 = qb * 128 + w * 32;
    h8 qf[2][2];
#pragma unroll
    for (int m = 0; m < 2; ++m)
#pragma unroll
        for (int kk = 0; kk < 2; ++kk)
            qf[m][kk] = *(const h8*)(Qh + base + (size_t)(q0 + m * 16 + l15) * 64 + kk * 32 + l4 * 8);

    f4 O[2][4] = {};
    float mrow[2][4], lrow[2][4];
#pragma unroll
    for (int m = 0; m < 2; ++m)
#pragma unroll
        for (int i = 0; i < 4; ++i) { mrow[m][i] = -1e30f; lrow[m][i] = 0.f; }

    const int srow = tid >> 2, sc0 = (tid & 3) * 8;
    const _Float16* Kg = Kh + base + (size_t)srow * 64 + sc0;       // advance by kb*64*64
    const _Float16* Vg = Vt + base + (size_t)srow * 2048 + sc0;     // advance by kb*64
    _Float16* Pw = Ps + w * 32 * 72;
    const int kbmax = 2 * qb + 1;

    // prologue: stage tile 0
    {
        h8 k0 = *(const h8*)(Kg);
        h8 k1 = *(const h8*)(Kg + 32);
        h8 v0 = *(const h8*)(Vg);
        h8 v1 = *(const h8*)(Vg + 32);
        *(h8*)(&Ks[srow * 72 + sc0]) = k0;
        *(h8*)(&Ks[srow * 72 + sc0 + 32]) = k1;
        *(h8*)(&Vs[srow * 72 + sc0]) = v0;
        *(h8*)(&Vs[srow * 72 + sc0 + 32]) = v1;
    }
    __syncthreads();

    for (int kb = 0; kb <= kbmax; ++kb) {
        const bool pre = (kb < kbmax);
        h8 kn0, kn1, vn0, vn1;
        if (pre) {  // T14: issue next-tile loads early; consumed after the barrier
            const _Float16* Kp = Kg + (size_t)(kb + 1) * 64 * 64;
            const _Float16* Vp = Vg + (kb + 1) * 64;
            kn0 = *(const h8*)(Kp);
            kn1 = *(const h8*)(Kp + 32);
            vn0 = *(const h8*)(Vp);
            vn1 = *(const h8*)(Vp + 32);
        }

        // QK^T (Q pre-scaled by 1/8 in GEMM epilogue)
        f4 s[2][4];
        __builtin_amdgcn_s_setprio(1);
#pragma unroll
        for (int nt = 0; nt < 4; ++nt) {
            h8 kf0 = *(const h8*)(&Ks[(nt * 16 + l15) * 72 + l4 * 8]);
            h8 kf1 = *(const h8*)(&Ks[(nt * 16 + l15) * 72 + 32 + l4 * 8]);
#pragma unroll
            for (int m = 0; m < 2; ++m) {
                f4 c = {};
                c = MFMA16(qf[m][0], kf0, c);
                c = MFMA16(qf[m][1], kf1, c);
                s[m][nt] = c;
            }
        }
        __builtin_amdgcn_s_setprio(0);

        // causal mask (only last two tiles can touch the diagonal) + online softmax
        const bool diag = (kb >= 2 * qb);
        float pm[2][4];
#pragma unroll
        for (int m = 0; m < 2; ++m)
#pragma unroll
            for (int i = 0; i < 4; ++i) pm[m][i] = -1e30f;
#pragma unroll
        for (int m = 0; m < 2; ++m)
#pragma unroll
            for (int nt = 0; nt < 4; ++nt)
#pragma unroll
                for (int i = 0; i < 4; ++i) {
                    float v = s[m][nt][i];
                    if (diag) {
                        int key = kb * 64 + nt * 16 + l15;
                        int row = q0 + m * 16 + l4 * 4 + i;
                        if (key > row) v = -1e30f;
                    }
                    s[m][nt][i] = v;
                    pm[m][i] = fmaxf(pm[m][i], v);
                }
#pragma unroll
        for (int mm = 1; mm < 16; mm <<= 1)
#pragma unroll
            for (int m = 0; m < 2; ++m)
#pragma unroll
                for (int i = 0; i < 4; ++i)
                    pm[m][i] = fmaxf(pm[m][i], __shfl_xor(pm[m][i], mm));

        float rs[2][4];
#pragma unroll
        for (int m = 0; m < 2; ++m)
#pragma unroll
            for (int i = 0; i < 4; ++i) {
                float mn = fmaxf(mrow[m][i], pm[m][i]);
                float scl = __expf(mrow[m][i] - mn);
                mrow[m][i] = mn;
                lrow[m][i] *= scl;
                rs[m][i] = 0.f;
#pragma unroll
                for (int dt = 0; dt < 4; ++dt) O[m][dt][i] *= scl;
            }
#pragma unroll
        for (int m = 0; m < 2; ++m)
#pragma unroll
            for (int nt = 0; nt < 4; ++nt)
#pragma unroll
                for (int i = 0; i < 4; ++i) {
                    float p = __expf(s[m][nt][i] - mrow[m][i]);
                    rs[m][i] += p;
                    Pw[(m * 16 + l4 * 4 + i) * 72 + nt * 16 + l15] = (_Float16)p;
                }
#pragma unroll
        for (int mm = 1; mm < 16; mm <<= 1)
#pragma unroll
            for (int m = 0; m < 2; ++m)
#pragma unroll
                for (int i = 0; i < 4; ++i) rs[m][i] += __shfl_xor(rs[m][i], mm);
#pragma unroll
        for (int m = 0; m < 2; ++m)
#pragma unroll
            for (int i = 0; i < 4; ++i) lrow[m][i] += rs[m][i];

        asm volatile("s_waitcnt lgkmcnt(0)" ::: "memory");   // P writes -> P reads (wave-private)

        // PV
        h8 pf[2][2];
#pragma unroll
        for (int m = 0; m < 2; ++m)
#pragma unroll
            for (int kk = 0; kk < 2; ++kk)
                pf[m][kk] = *(const h8*)(&Pw[(m * 16 + l15) * 72 + kk * 32 + l4 * 8]);
        __builtin_amdgcn_s_setprio(1);
#pragma unroll
        for (int dt = 0; dt < 4; ++dt) {
            h8 vf0 = *(const h8*)(&Vs[(dt * 16 + l15) * 72 + l4 * 8]);
            h8 vf1 = *(const h8*)(&Vs[(dt * 16 + l15) * 72 + 32 + l4 * 8]);
#pragma unroll
            for (int m = 0; m < 2; ++m) {
                O[m][dt] = MFMA16(pf[m][0], vf0, O[m][dt]);
                O[m][dt] = MFMA16(pf[m][1], vf1, O[m][dt]);
            }
        }
        __builtin_amdgcn_s_setprio(0);

        __syncthreads();
        if (pre) {
            *(h8*)(&Ks[srow * 72 + sc0]) = kn0;
            *(h8*)(&Ks[srow * 72 + sc0 + 32]) = kn1;
            *(h8*)(&Vs[srow * 72 + sc0]) = vn0;
            *(h8*)(&Vs[srow * 72 + sc0 + 32]) = vn1;
            __syncthreads();
        }
    }

    // epilogue: normalize and write Y (B,T,C) f16
    const int b = bh >> 4, h = bh & 15;
#pragma unroll
    for (int m = 0; m < 2; ++m)
#pragma unroll
        for (int i = 0; i < 4; ++i) {
            float inv = 1.0f / lrow[m][i];
            int q = q0 + m * 16 + l4 * 4 + i;
            _Float16* yp = Yh + ((size_t)(b * 2048 + q)) * 1024 + h * 64;
#pragma unroll
            for (int dt = 0; dt < 4; ++dt)
                yp[dt * 16 + l15] = (_Float16)(O[m][dt][i] * inv);
        }
}

extern "C" void kernel_launch(void* const* d_in, const int* in_sizes, int n_in,
                              void* d_out, int out_size, void* d_ws, size_t ws_size,
                              hipStream_t stream) {
    const float* x  = (const float*)d_in[0];
    const float* Wa = (const float*)d_in[1];
    const float* ba = (const float*)d_in[2];
    const float* Wp = (const float*)d_in[3];
    const float* bp = (const float*)d_in[4];
    float* out = (float*)d_out;

    _Float16* ws = (_Float16*)d_ws;
    const size_t SZ_X = (size_t)8192 * 1024;
    const size_t SZ_WA = (size_t)3072 * 1024;
    const size_t SZ_WP = (size_t)1024 * 1024;
    const size_t SZ_H = (size_t)64 * 2048 * 64;
    _Float16* xh  = ws;
    _Float16* WaT = xh + SZ_X;
    _Float16* WpT = WaT + SZ_WA;
    _Float16* Qh  = WpT + SZ_WP;
    _Float16* Kh  = Qh + SZ_H;
    _Float16* Vth = Kh + SZ_H;    // V transposed: (bh, d, t)
    _Float16* Yh  = Vth + SZ_H;

    k_f32_to_f16<<<8192, 256, 0, stream>>>(x, xh, (int)(SZ_X / 4));
    k_transpose_f16<<<dim3(16, 48), 256, 0, stream>>>(Wa, WaT, 1024, 3072);
    k_transpose_f16<<<dim3(16, 16), 256, 0, stream>>>(Wp, WpT, 1024, 1024);
    k_gemm<0><<<dim3(64, 24), 256, 0, stream>>>(xh, WaT, ba, Qh, Kh, Vth, nullptr,
                                                8192, 3072, 1024);
    k_attn<<<1024, 256, 0, stream>>>(Qh, Kh, Vth, Yh);
    k_gemm<1><<<dim3(64, 8), 256, 0, stream>>>(Yh, WpT, bp, nullptr, nullptr, nullptr,
                                               out, 8192, 1024, 1024);
}

// Round 4
// 258.628 us; speedup vs baseline: 1.5026x; 1.3458x over previous
//
#include <hip/hip_runtime.h>

typedef __attribute__((ext_vector_type(8))) _Float16 h8;
typedef __attribute__((ext_vector_type(4))) _Float16 h4;
typedef __attribute__((ext_vector_type(4))) float f4;
typedef __attribute__((ext_vector_type(16))) float f16x;
typedef __attribute__((ext_vector_type(4))) unsigned u4;

#define MFMA16(a,b,c) __builtin_amdgcn_mfma_f32_16x16x32_f16(a,b,c,0,0,0)
#define MFMA32(a,b,c) __builtin_amdgcn_mfma_f32_32x32x16_f16(a,b,c,0,0,0)

// partner-half (lane ^ 32) value, semantics-guaranteed
__device__ inline float swap_half(float x) { return __shfl_xor(x, 32, 64); }

// ---------------- fp32 -> f16 elementwise (vectorized) ----------------
__global__ __launch_bounds__(256) void k_f32_to_f16(const float* __restrict__ in,
                                                    _Float16* __restrict__ out, int n4) {
    int i = blockIdx.x * 256 + threadIdx.x;
    if (i < n4) {
        float4 v = ((const float4*)in)[i];
        h4 h;
        h[0] = (_Float16)v.x; h[1] = (_Float16)v.y;
        h[2] = (_Float16)v.z; h[3] = (_Float16)v.w;
        ((h4*)out)[i] = h;
    }
}

// ---------------- fp32 (K,N) -> f16 (N,K) tiled transpose ----------------
__global__ __launch_bounds__(256) void k_transpose_f16(const float* __restrict__ W,
                                                       _Float16* __restrict__ Wt,
                                                       int K, int N) {
    __shared__ float tile[64 * 68];
    const int k0 = blockIdx.x * 64, n0 = blockIdx.y * 64;
    const int t = threadIdx.x;
    const int tr = t >> 4;
    const int tc = t & 15;
#pragma unroll
    for (int i = 0; i < 4; ++i) {
        int r = tr + i * 16;
        float4 v = *(const float4*)(W + (size_t)(k0 + r) * N + n0 + tc * 4);
        *(float4*)(&tile[r * 68 + tc * 4]) = v;
    }
    __syncthreads();
#pragma unroll
    for (int i = 0; i < 4; ++i) {
        int nl = tr + i * 16;
        h4 hv;
#pragma unroll
        for (int j = 0; j < 4; ++j)
            hv[j] = (_Float16)tile[(tc * 4 + j) * 68 + nl];
        *(h4*)(Wt + (size_t)(n0 + nl) * K + k0 + tc * 4) = hv;
    }
}

// ---------------- 128x128 MFMA GEMM: C = A(MxK) * Bt(NxK)^T + bias ----------------
// MODE 0: scatter into Q/K (B,H,T,64) and V^T (B,H,64,T) f16 buffers; Q pre-scaled 1/8.
// MODE 1: fp32 out.
template <int MODE>
__global__ __launch_bounds__(256) void k_gemm(const _Float16* __restrict__ A,
                                              const _Float16* __restrict__ Bt,
                                              const float* __restrict__ bias,
                                              _Float16* __restrict__ oQ,
                                              _Float16* __restrict__ oK,
                                              _Float16* __restrict__ oV,
                                              float* __restrict__ oF,
                                              int M, int N, int K) {
    __shared__ _Float16 As[128 * 40];
    __shared__ _Float16 Bs[128 * 40];
    const int tid = threadIdx.x;
    const int lane = tid & 63, wv = tid >> 6;
    const int wm = wv >> 1, wn = wv & 1;
    const int l15 = lane & 15, l4 = lane >> 4;
    const int bm = blockIdx.x * 128, bn = blockIdx.y * 128;
    const int lr = tid >> 2, lc = (tid & 3) * 8;
    f4 acc[4][4] = {};
    const _Float16* Ap = A + (size_t)(bm + lr) * K + lc;
    const _Float16* Bp = Bt + (size_t)(bn + lr) * K + lc;

    for (int k0 = 0; k0 < K; k0 += 32) {
        __syncthreads();
        h8 a0 = *(const h8*)(Ap + k0);
        h8 a1 = *(const h8*)(Ap + (size_t)64 * K + k0);
        h8 b0 = *(const h8*)(Bp + k0);
        h8 b1 = *(const h8*)(Bp + (size_t)64 * K + k0);
        *(h8*)(&As[lr * 40 + lc]) = a0;
        *(h8*)(&As[(lr + 64) * 40 + lc]) = a1;
        *(h8*)(&Bs[lr * 40 + lc]) = b0;
        *(h8*)(&Bs[(lr + 64) * 40 + lc]) = b1;
        __syncthreads();
        h8 af[4], bf[4];
#pragma unroll
        for (int i = 0; i < 4; ++i)
            af[i] = *(const h8*)(&As[(wm * 64 + i * 16 + l15) * 40 + l4 * 8]);
#pragma unroll
        for (int i = 0; i < 4; ++i)
            bf[i] = *(const h8*)(&Bs[(wn * 64 + i * 16 + l15) * 40 + l4 * 8]);
#pragma unroll
        for (int mi = 0; mi < 4; ++mi)
#pragma unroll
            for (int ni = 0; ni < 4; ++ni)
                acc[mi][ni] = MFMA16(af[mi], bf[ni], acc[mi][ni]);
    }

#pragma unroll
    for (int mi = 0; mi < 4; ++mi) {
#pragma unroll
        for (int ni = 0; ni < 4; ++ni) {
            int col = bn + wn * 64 + ni * 16 + l15;
            float bv = bias[col];
            int rb = bm + wm * 64 + mi * 16 + l4 * 4;
            if (MODE == 0) {
                int which = col >> 10, n1 = col & 1023;
                int hh = n1 >> 6, dd = n1 & 63;
                if (which == 2) {
                    int b = rb >> 11, tq = rb & 2047;
                    h4 pv;
#pragma unroll
                    for (int i = 0; i < 4; ++i) pv[i] = (_Float16)(acc[mi][ni][i] + bv);
                    *(h4*)(oV + ((size_t)(b * 16 + hh) * 64 + dd) * 2048 + tq) = pv;
                } else {
                    _Float16* dst = which == 0 ? oQ : oK;
                    const float scl = which == 0 ? 0.125f : 1.0f;
#pragma unroll
                    for (int i = 0; i < 4; ++i) {
                        int row = rb + i;
                        int b = row >> 11, tq = row & 2047;
                        dst[(((size_t)b * 16 + hh) * 2048 + tq) * 64 + dd] =
                            (_Float16)((acc[mi][ni][i] + bv) * scl);
                    }
                }
            } else {
#pragma unroll
                for (int i = 0; i < 4; ++i)
                    oF[(size_t)(rb + i) * N + col] = acc[mi][ni][i] + bv;
            }
        }
    }
}

// ---------------- causal flash attention, swapped-operand 32x32 MFMA ----------------
// Block: 128 q-rows, 4 waves x 32 q each. Lane-local softmax; partner exchange via shfl_xor(32).
// LDS byte-swizzle for K/V tiles (row stride 128B): cb ^= (row&7)<<4.
#define SWZI(row, cb) ((((row) << 7) + ((cb) ^ ((((row) & 7) << 4)))) >> 1)

__global__ __launch_bounds__(256) void k_attn(const _Float16* __restrict__ Qh,
                                              const _Float16* __restrict__ Kh,
                                              const _Float16* __restrict__ Vt,
                                              _Float16* __restrict__ Yh) {
    __shared__ _Float16 Ks[4096];          // [64 key][64 d] swizzled
    __shared__ _Float16 Vs[4096];          // [64 d][64 key] swizzled
    __shared__ _Float16 Os[128 * 72];      // epilogue transpose buffer
    const int qb = 15 - (blockIdx.x & 15); // long blocks first
    const int bh = blockIdx.x >> 4;
    const int tid = threadIdx.x, lane = tid & 63, w = tid >> 6;
    const int l31 = lane & 31, hi = lane >> 5;
    const int h16 = hi * 16, h4o = hi * 4;
    const size_t base = (size_t)bh * 2048 * 64;

    const int qabs = qb * 128 + w * 32 + l31;
    h8 qf[4];
#pragma unroll
    for (int dk = 0; dk < 4; ++dk)
        qf[dk] = *(const h8*)(Qh + base + (size_t)qabs * 64 + dk * 16 + hi * 8);

    f16x O0 = {}, O1 = {};
    float m = -1e30f, l = 0.f;

    const int srow = tid >> 2;             // 0..63
    const int scb = (tid & 3) * 32;        // byte col base
    const _Float16* Kg = Kh + base + (size_t)srow * 64 + (scb >> 1);
    const _Float16* Vg = Vt + base + (size_t)srow * 2048 + (scb >> 1);
    const int kbb = 2 * qb + 1;            // block's last tile
    const int kbw = 2 * qb + (w >> 1);     // this wave's last tile

    // prologue: stage tile 0
    {
        h8 k0 = *(const h8*)(Kg);
        h8 k1 = *(const h8*)(Kg + 8);
        h8 v0 = *(const h8*)(Vg);
        h8 v1 = *(const h8*)(Vg + 8);
        *(h8*)(&Ks[SWZI(srow, scb)]) = k0;
        *(h8*)(&Ks[SWZI(srow, scb + 16)]) = k1;
        *(h8*)(&Vs[SWZI(srow, scb)]) = v0;
        *(h8*)(&Vs[SWZI(srow, scb + 16)]) = v1;
    }
    __syncthreads();

    for (int kb = 0; kb <= kbb; ++kb) {
        const bool pre = (kb < kbb);
        h8 kn0, kn1, vn0, vn1;
        if (pre) {  // T14: issue next-tile loads early
            const _Float16* Kp = Kg + (size_t)(kb + 1) * 4096;
            const _Float16* Vp = Vg + (size_t)(kb + 1) * 64;
            kn0 = *(const h8*)(Kp);
            kn1 = *(const h8*)(Kp + 8);
            vn0 = *(const h8*)(Vp);
            vn1 = *(const h8*)(Vp + 8);
        }

        if (kb <= kbw) {
            // ---- QK^T swapped: S^T[key][q], lane=q, regs=keys ----
            f16x S0 = {}, S1 = {};
            __builtin_amdgcn_s_setprio(1);
#pragma unroll
            for (int dk = 0; dk < 4; ++dk) {
                h8 kf0 = *(const h8*)(&Ks[SWZI(l31, dk * 32 + h16)]);
                h8 kf1 = *(const h8*)(&Ks[SWZI(32 + l31, dk * 32 + h16)]);
                S0 = MFMA32(kf0, qf[dk], S0);
                S1 = MFMA32(kf1, qf[dk], S1);
            }
            __builtin_amdgcn_s_setprio(0);

            // ---- causal mask (wave's final tile only) ----
            if (kb == kbw) {
#pragma unroll
                for (int r = 0; r < 16; ++r) {
                    int key = kb * 64 + (r & 3) + 8 * (r >> 2) + h4o;
                    if (key > qabs) S0[r] = -1e30f;
                    if (key + 32 > qabs) S1[r] = -1e30f;
                }
            }

            // ---- in-register online softmax (one cross-lane exchange per reduce) ----
            float t[16];
#pragma unroll
            for (int r = 0; r < 16; ++r) t[r] = fmaxf(S0[r], S1[r]);
#pragma unroll
            for (int st = 8; st >= 1; st >>= 1)
#pragma unroll
                for (int r = 0; r < st; ++r) t[r] = fmaxf(t[r], t[r + st]);
            float pm = fmaxf(t[0], swap_half(t[0]));
            float mnew = fmaxf(m, pm);
            float scl = __expf(m - mnew);
            m = mnew;
#pragma unroll
            for (int r = 0; r < 16; ++r) {
                S0[r] = __expf(S0[r] - mnew);
                S1[r] = __expf(S1[r] - mnew);
            }
#pragma unroll
            for (int r = 0; r < 16; ++r) t[r] = S0[r] + S1[r];
#pragma unroll
            for (int st = 8; st >= 1; st >>= 1)
#pragma unroll
                for (int r = 0; r < st; ++r) t[r] += t[r + st];
            float rs = t[0] + swap_half(t[0]);
            l = l * scl + rs;
#pragma unroll
            for (int r = 0; r < 16; ++r) { O0[r] *= scl; O1[r] *= scl; }

            // ---- T12: pack P into PV B-frags (word exchange via shfl_xor 32) ----
            h8 pb[4];
#pragma unroll
            for (int kk = 0; kk < 4; ++kk) {
                const int bb = (kk & 1) * 8;
                unsigned W0, W1, W2, W3;
                if (kk < 2) {
                    W0 = __builtin_bit_cast(unsigned, __builtin_amdgcn_cvt_pkrtz(S0[bb + 0], S0[bb + 1]));
                    W1 = __builtin_bit_cast(unsigned, __builtin_amdgcn_cvt_pkrtz(S0[bb + 2], S0[bb + 3]));
                    W2 = __builtin_bit_cast(unsigned, __builtin_amdgcn_cvt_pkrtz(S0[bb + 4], S0[bb + 5]));
                    W3 = __builtin_bit_cast(unsigned, __builtin_amdgcn_cvt_pkrtz(S0[bb + 6], S0[bb + 7]));
                } else {
                    W0 = __builtin_bit_cast(unsigned, __builtin_amdgcn_cvt_pkrtz(S1[bb + 0], S1[bb + 1]));
                    W1 = __builtin_bit_cast(unsigned, __builtin_amdgcn_cvt_pkrtz(S1[bb + 2], S1[bb + 3]));
                    W2 = __builtin_bit_cast(unsigned, __builtin_amdgcn_cvt_pkrtz(S1[bb + 4], S1[bb + 5]));
                    W3 = __builtin_bit_cast(unsigned, __builtin_amdgcn_cvt_pkrtz(S1[bb + 6], S1[bb + 7]));
                }
                // lo lane needs partner's {W0,W1}; hi lane needs partner's {W2,W3}
                unsigned E0 = (unsigned)__shfl_xor((int)(hi ? W0 : W2), 32, 64);
                unsigned E1 = (unsigned)__shfl_xor((int)(hi ? W1 : W3), 32, 64);
                u4 wvv;
                wvv[0] = hi ? E0 : W0;
                wvv[1] = hi ? E1 : W1;
                wvv[2] = hi ? W2 : E0;
                wvv[3] = hi ? W3 : E1;
                pb[kk] = __builtin_bit_cast(h8, wvv);
            }

            // ---- PV swapped: O^T[d][q] += V^T-frag x P-frag ----
            __builtin_amdgcn_s_setprio(1);
#pragma unroll
            for (int kk = 0; kk < 4; ++kk) {
                h8 vf0 = *(const h8*)(&Vs[SWZI(l31, kk * 32 + h16)]);
                h8 vf1 = *(const h8*)(&Vs[SWZI(32 + l31, kk * 32 + h16)]);
                O0 = MFMA32(vf0, pb[kk], O0);
                O1 = MFMA32(vf1, pb[kk], O1);
            }
            __builtin_amdgcn_s_setprio(0);
        }

        __syncthreads();
        if (pre) {
            *(h8*)(&Ks[SWZI(srow, scb)]) = kn0;
            *(h8*)(&Ks[SWZI(srow, scb + 16)]) = kn1;
            *(h8*)(&Vs[SWZI(srow, scb)]) = vn0;
            *(h8*)(&Vs[SWZI(srow, scb + 16)]) = vn1;
            __syncthreads();
        }
    }

    // ---- epilogue: O^T (lane=q, regs=d) -> LDS -> coalesced global ----
    {
        float inv = 1.0f / l;
        _Float16* ow = Os + (size_t)(w * 32 + l31) * 72;
#pragma unroll
        for (int r = 0; r < 16; ++r) {
            int d0 = (r & 3) + 8 * (r >> 2) + h4o;
            ow[d0] = (_Float16)(O0[r] * inv);
            ow[d0 + 32] = (_Float16)(O1[r] * inv);
        }
    }
    __syncthreads();
    {
        const int b = bh >> 4, head = bh & 15;
        const int row = tid >> 1;
#pragma unroll
        for (int i = 0; i < 4; ++i) {
            int seg = (tid & 1) * 4 + i;
            h8 v = *(const h8*)(&Os[row * 72 + seg * 8]);
            *(h8*)(Yh + ((size_t)(b * 2048 + qb * 128 + row)) * 1024 + head * 64 + seg * 8) = v;
        }
    }
}

extern "C" void kernel_launch(void* const* d_in, const int* in_sizes, int n_in,
                              void* d_out, int out_size, void* d_ws, size_t ws_size,
                              hipStream_t stream) {
    const float* x  = (const float*)d_in[0];
    const float* Wa = (const float*)d_in[1];
    const float* ba = (const float*)d_in[2];
    const float* Wp = (const float*)d_in[3];
    const float* bp = (const float*)d_in[4];
    float* out = (float*)d_out;

    _Float16* ws = (_Float16*)d_ws;
    const size_t SZ_X = (size_t)8192 * 1024;
    const size_t SZ_WA = (size_t)3072 * 1024;
    const size_t SZ_WP = (size_t)1024 * 1024;
    const size_t SZ_H = (size_t)64 * 2048 * 64;
    _Float16* xh  = ws;
    _Float16* WaT = xh + SZ_X;
    _Float16* WpT = WaT + SZ_WA;
    _Float16* Qh  = WpT + SZ_WP;
    _Float16* Kh  = Qh + SZ_H;
    _Float16* Vth = Kh + SZ_H;    // V transposed: (bh, d, t)
    _Float16* Yh  = Vth + SZ_H;

    k_f32_to_f16<<<8192, 256, 0, stream>>>(x, xh, (int)(SZ_X / 4));
    k_transpose_f16<<<dim3(16, 48), 256, 0, stream>>>(Wa, WaT, 1024, 3072);
    k_transpose_f16<<<dim3(16, 16), 256, 0, stream>>>(Wp, WpT, 1024, 1024);
    k_gemm<0><<<dim3(64, 24), 256, 0, stream>>>(xh, WaT, ba, Qh, Kh, Vth, nullptr,
                                                8192, 3072, 1024);
    k_attn<<<1024, 256, 0, stream>>>(Qh, Kh, Vth, Yh);
    k_gemm<1><<<dim3(64, 8), 256, 0, stream>>>(Yh, WpT, bp, nullptr, nullptr, nullptr,
                                               out, 8192, 1024, 1024);
}

// Round 5
// 197.916 us; speedup vs baseline: 1.9635x; 1.3068x over previous
//
#include <hip/hip_runtime.h>

typedef __attribute__((ext_vector_type(8))) _Float16 h8;
typedef __attribute__((ext_vector_type(4))) _Float16 h4;
typedef __attribute__((ext_vector_type(4))) float f4;
typedef __attribute__((ext_vector_type(16))) float f16x;
typedef __attribute__((ext_vector_type(4))) unsigned u4;

#define MFMA16(a,b,c) __builtin_amdgcn_mfma_f32_16x16x32_f16(a,b,c,0,0,0)
#define MFMA32(a,b,c) __builtin_amdgcn_mfma_f32_32x32x16_f16(a,b,c,0,0,0)

// partner-half (lane ^ 32) value, semantics-guaranteed
__device__ inline float swap_half(float x) { return __shfl_xor(x, 32, 64); }

// ---------------- fp32 -> f16 elementwise (vectorized) ----------------
__global__ __launch_bounds__(256) void k_f32_to_f16(const float* __restrict__ in,
                                                    _Float16* __restrict__ out, int n4) {
    int i = blockIdx.x * 256 + threadIdx.x;
    if (i < n4) {
        float4 v = ((const float4*)in)[i];
        h4 h;
        h[0] = (_Float16)v.x; h[1] = (_Float16)v.y;
        h[2] = (_Float16)v.z; h[3] = (_Float16)v.w;
        ((h4*)out)[i] = h;
    }
}

// ---------------- fp32 (K,N) -> f16 (N,K) tiled transpose ----------------
__global__ __launch_bounds__(256) void k_transpose_f16(const float* __restrict__ W,
                                                       _Float16* __restrict__ Wt,
                                                       int K, int N) {
    __shared__ float tile[64 * 68];
    const int k0 = blockIdx.x * 64, n0 = blockIdx.y * 64;
    const int t = threadIdx.x;
    const int tr = t >> 4;
    const int tc = t & 15;
#pragma unroll
    for (int i = 0; i < 4; ++i) {
        int r = tr + i * 16;
        float4 v = *(const float4*)(W + (size_t)(k0 + r) * N + n0 + tc * 4);
        *(float4*)(&tile[r * 68 + tc * 4]) = v;
    }
    __syncthreads();
#pragma unroll
    for (int i = 0; i < 4; ++i) {
        int nl = tr + i * 16;
        h4 hv;
#pragma unroll
        for (int j = 0; j < 4; ++j)
            hv[j] = (_Float16)tile[(tc * 4 + j) * 68 + nl];
        *(h4*)(Wt + (size_t)(n0 + nl) * K + k0 + tc * 4) = hv;
    }
}

// ---------------- 128x128 MFMA GEMM: C = A(MxK) * Bt(NxK)^T + bias ----------------
// MODE 0: scatter into Q/K (B,H,T,64) and V^T (B,H,64,T) f16 buffers;
//         Q pre-scaled by 0.125*log2(e) (attention works in exp2 domain).
// MODE 1: fp32 out.
template <int MODE>
__global__ __launch_bounds__(256) void k_gemm(const _Float16* __restrict__ A,
                                              const _Float16* __restrict__ Bt,
                                              const float* __restrict__ bias,
                                              _Float16* __restrict__ oQ,
                                              _Float16* __restrict__ oK,
                                              _Float16* __restrict__ oV,
                                              float* __restrict__ oF,
                                              int M, int N, int K) {
    __shared__ _Float16 As[128 * 40];
    __shared__ _Float16 Bs[128 * 40];
    const int tid = threadIdx.x;
    const int lane = tid & 63, wv = tid >> 6;
    const int wm = wv >> 1, wn = wv & 1;
    const int l15 = lane & 15, l4 = lane >> 4;
    const int bm = blockIdx.x * 128, bn = blockIdx.y * 128;
    const int lr = tid >> 2, lc = (tid & 3) * 8;
    f4 acc[4][4] = {};
    const _Float16* Ap = A + (size_t)(bm + lr) * K + lc;
    const _Float16* Bp = Bt + (size_t)(bn + lr) * K + lc;

    for (int k0 = 0; k0 < K; k0 += 32) {
        __syncthreads();
        h8 a0 = *(const h8*)(Ap + k0);
        h8 a1 = *(const h8*)(Ap + (size_t)64 * K + k0);
        h8 b0 = *(const h8*)(Bp + k0);
        h8 b1 = *(const h8*)(Bp + (size_t)64 * K + k0);
        *(h8*)(&As[lr * 40 + lc]) = a0;
        *(h8*)(&As[(lr + 64) * 40 + lc]) = a1;
        *(h8*)(&Bs[lr * 40 + lc]) = b0;
        *(h8*)(&Bs[(lr + 64) * 40 + lc]) = b1;
        __syncthreads();
        h8 af[4], bf[4];
#pragma unroll
        for (int i = 0; i < 4; ++i)
            af[i] = *(const h8*)(&As[(wm * 64 + i * 16 + l15) * 40 + l4 * 8]);
#pragma unroll
        for (int i = 0; i < 4; ++i)
            bf[i] = *(const h8*)(&Bs[(wn * 64 + i * 16 + l15) * 40 + l4 * 8]);
#pragma unroll
        for (int mi = 0; mi < 4; ++mi)
#pragma unroll
            for (int ni = 0; ni < 4; ++ni)
                acc[mi][ni] = MFMA16(af[mi], bf[ni], acc[mi][ni]);
    }

#pragma unroll
    for (int mi = 0; mi < 4; ++mi) {
#pragma unroll
        for (int ni = 0; ni < 4; ++ni) {
            int col = bn + wn * 64 + ni * 16 + l15;
            float bv = bias[col];
            int rb = bm + wm * 64 + mi * 16 + l4 * 4;
            if (MODE == 0) {
                int which = col >> 10, n1 = col & 1023;
                int hh = n1 >> 6, dd = n1 & 63;
                if (which == 2) {
                    int b = rb >> 11, tq = rb & 2047;
                    h4 pv;
#pragma unroll
                    for (int i = 0; i < 4; ++i) pv[i] = (_Float16)(acc[mi][ni][i] + bv);
                    *(h4*)(oV + ((size_t)(b * 16 + hh) * 64 + dd) * 2048 + tq) = pv;
                } else {
                    _Float16* dst = which == 0 ? oQ : oK;
                    const float scl = which == 0 ? 0.18033688011112042f : 1.0f; // 0.125*log2(e)
#pragma unroll
                    for (int i = 0; i < 4; ++i) {
                        int row = rb + i;
                        int b = row >> 11, tq = row & 2047;
                        dst[(((size_t)b * 16 + hh) * 2048 + tq) * 64 + dd] =
                            (_Float16)((acc[mi][ni][i] + bv) * scl);
                    }
                }
            } else {
#pragma unroll
                for (int i = 0; i < 4; ++i)
                    oF[(size_t)(rb + i) * N + col] = acc[mi][ni][i] + bv;
            }
        }
    }
}

// ---------------- causal flash attention: 1 wave / 32 q-rows per block ----------------
// No barriers (wave-private LDS, DS in-order). Swapped-operand 32x32 MFMA,
// lane-local softmax in exp2 domain, T13 defer-rescale, T14 reg-staged prefetch.
// LDS byte-swizzle for K/V tiles (row stride 128B): cb ^= (row&7)<<4.
#define SWZI(row, cb) ((((row) << 7) + ((cb) ^ ((((row) & 7) << 4)))) >> 1)

__global__ __launch_bounds__(64) void k_attn(const _Float16* __restrict__ Qh,
                                             const _Float16* __restrict__ Kh,
                                             const _Float16* __restrict__ Vt,
                                             _Float16* __restrict__ Yh) {
    __shared__ _Float16 lds[8192];         // [0..4095]=K tile, [4096..]=V tile; reused in epilogue
    const int bid = blockIdx.x;
    const int bh = bid & 63;               // consecutive bids -> different bh -> XCD-local K/V
    const int qb = 63 - (bid >> 6);        // long q-tiles dispatched first
    const int t = threadIdx.x;
    const int l31 = t & 31, hi = t >> 5;
    const int h16 = hi * 16, h4o = hi * 4;
    const size_t base = (size_t)bh * 2048 * 64;

    const int qabs = qb * 32 + l31;
    h8 qf[4];
#pragma unroll
    for (int dk = 0; dk < 4; ++dk)
        qf[dk] = *(const h8*)(Qh + base + (size_t)qabs * 64 + dk * 16 + hi * 8);

    f16x O0 = {}, O1 = {};
    float m = -1e30f, l = 0.f;

    // staging geometry: instr j covers rows j*8..j*8+7, 8 lanes x 16B per row
    const int sr = t >> 3;                 // row-in-octet 0..7
    const int sc = (t & 7) * 8;            // element col base
    const _Float16* Kg = Kh + base + (size_t)sr * 64 + sc;
    const _Float16* Vg = Vt + base + (size_t)sr * 2048 + sc;
    const int kbw = qb >> 1;               // wave's last key tile

    // prologue: stage tile 0
    {
        h8 kn[8], vn[8];
#pragma unroll
        for (int j = 0; j < 8; ++j) kn[j] = *(const h8*)(Kg + j * 512);
#pragma unroll
        for (int j = 0; j < 8; ++j) vn[j] = *(const h8*)(Vg + j * 16384);
#pragma unroll
        for (int j = 0; j < 8; ++j) *(h8*)(&lds[SWZI(j * 8 + sr, (t & 7) * 16)]) = kn[j];
#pragma unroll
        for (int j = 0; j < 8; ++j) *(h8*)(&lds[4096 + SWZI(j * 8 + sr, (t & 7) * 16)]) = vn[j];
    }
    asm volatile("s_waitcnt lgkmcnt(0)" ::: "memory");
    __builtin_amdgcn_sched_barrier(0);

    for (int kb = 0; kb <= kbw; ++kb) {
        const bool pre = (kb < kbw);
        h8 kn[8], vn[8];
        if (pre) {  // T14: issue next K tile early
#pragma unroll
            for (int j = 0; j < 8; ++j)
                kn[j] = *(const h8*)(Kg + (size_t)(kb + 1) * 4096 + j * 512);
        }

        // ---- QK^T swapped: S^T[key][q], lane=q, regs=keys (log2 domain) ----
        f16x S0 = {}, S1 = {};
        __builtin_amdgcn_s_setprio(1);
#pragma unroll
        for (int dk = 0; dk < 4; ++dk) {
            h8 kf0 = *(const h8*)(&lds[SWZI(l31, dk * 32 + h16)]);
            h8 kf1 = *(const h8*)(&lds[SWZI(32 + l31, dk * 32 + h16)]);
            S0 = MFMA32(kf0, qf[dk], S0);
            S1 = MFMA32(kf1, qf[dk], S1);
        }
        __builtin_amdgcn_s_setprio(0);

        if (pre) {  // issue next V tile; latency hides under softmax
#pragma unroll
            for (int j = 0; j < 8; ++j)
                vn[j] = *(const h8*)(Vg + (size_t)(kb + 1) * 64 + j * 16384);
        }

        // ---- causal mask (final tile only) ----
        if (kb == kbw) {
#pragma unroll
            for (int r = 0; r < 16; ++r) {
                int key = kb * 64 + (r & 3) + 8 * (r >> 2) + h4o;
                if (key > qabs) S0[r] = -1e30f;
                if (key + 32 > qabs) S1[r] = -1e30f;
            }
        }

        // ---- in-register online softmax (exp2 domain, T13 defer-rescale) ----
        float tr[16];
#pragma unroll
        for (int r = 0; r < 16; ++r) tr[r] = fmaxf(S0[r], S1[r]);
#pragma unroll
        for (int st = 8; st >= 1; st >>= 1)
#pragma unroll
            for (int r = 0; r < st; ++r) tr[r] = fmaxf(tr[r], tr[r + st]);
        float pm = fmaxf(tr[0], swap_half(tr[0]));
        if (!__all(pm - m <= 8.f)) {       // rescale only when max really grew
            float mnew = fmaxf(m, pm);
            float scl = __builtin_amdgcn_exp2f(m - mnew);
            m = mnew;
            l *= scl;
#pragma unroll
            for (int r = 0; r < 16; ++r) { O0[r] *= scl; O1[r] *= scl; }
        }
#pragma unroll
        for (int r = 0; r < 16; ++r) {
            S0[r] = __builtin_amdgcn_exp2f(S0[r] - m);
            S1[r] = __builtin_amdgcn_exp2f(S1[r] - m);
        }
#pragma unroll
        for (int r = 0; r < 16; ++r) tr[r] = S0[r] + S1[r];
#pragma unroll
        for (int st = 8; st >= 1; st >>= 1)
#pragma unroll
            for (int r = 0; r < st; ++r) tr[r] += tr[r + st];
        l += tr[0] + swap_half(tr[0]);

        // ---- T12: pack P into PV B-frags (word exchange via shfl_xor 32) ----
        h8 pb[4];
#pragma unroll
        for (int kk = 0; kk < 4; ++kk) {
            const int bb = (kk & 1) * 8;
            unsigned W0, W1, W2, W3;
            if (kk < 2) {
                W0 = __builtin_bit_cast(unsigned, __builtin_amdgcn_cvt_pkrtz(S0[bb + 0], S0[bb + 1]));
                W1 = __builtin_bit_cast(unsigned, __builtin_amdgcn_cvt_pkrtz(S0[bb + 2], S0[bb + 3]));
                W2 = __builtin_bit_cast(unsigned, __builtin_amdgcn_cvt_pkrtz(S0[bb + 4], S0[bb + 5]));
                W3 = __builtin_bit_cast(unsigned, __builtin_amdgcn_cvt_pkrtz(S0[bb + 6], S0[bb + 7]));
            } else {
                W0 = __builtin_bit_cast(unsigned, __builtin_amdgcn_cvt_pkrtz(S1[bb + 0], S1[bb + 1]));
                W1 = __builtin_bit_cast(unsigned, __builtin_amdgcn_cvt_pkrtz(S1[bb + 2], S1[bb + 3]));
                W2 = __builtin_bit_cast(unsigned, __builtin_amdgcn_cvt_pkrtz(S1[bb + 4], S1[bb + 5]));
                W3 = __builtin_bit_cast(unsigned, __builtin_amdgcn_cvt_pkrtz(S1[bb + 6], S1[bb + 7]));
            }
            unsigned E0 = (unsigned)__shfl_xor((int)(hi ? W0 : W2), 32, 64);
            unsigned E1 = (unsigned)__shfl_xor((int)(hi ? W1 : W3), 32, 64);
            u4 wvv;
            wvv[0] = hi ? E0 : W0;
            wvv[1] = hi ? E1 : W1;
            wvv[2] = hi ? W2 : E0;
            wvv[3] = hi ? W3 : E1;
            pb[kk] = __builtin_bit_cast(h8, wvv);
        }

        // ---- PV swapped: O^T[d][q] += V^T-frag x P-frag ----
        __builtin_amdgcn_s_setprio(1);
#pragma unroll
        for (int kk = 0; kk < 4; ++kk) {
            h8 vf0 = *(const h8*)(&lds[4096 + SWZI(l31, kk * 32 + h16)]);
            h8 vf1 = *(const h8*)(&lds[4096 + SWZI(32 + l31, kk * 32 + h16)]);
            O0 = MFMA32(vf0, pb[kk], O0);
            O1 = MFMA32(vf1, pb[kk], O1);
        }
        __builtin_amdgcn_s_setprio(0);

        if (pre) {  // write next tile (DS in-order per wave; all frag reads already issued)
            asm volatile("s_waitcnt lgkmcnt(0)" ::: "memory");
            __builtin_amdgcn_sched_barrier(0);
#pragma unroll
            for (int j = 0; j < 8; ++j) *(h8*)(&lds[SWZI(j * 8 + sr, (t & 7) * 16)]) = kn[j];
#pragma unroll
            for (int j = 0; j < 8; ++j) *(h8*)(&lds[4096 + SWZI(j * 8 + sr, (t & 7) * 16)]) = vn[j];
        }
    }

    // ---- epilogue: O^T (lane=q, regs=d) -> LDS (reuse K area) -> coalesced global ----
    asm volatile("s_waitcnt lgkmcnt(0)" ::: "memory");
    __builtin_amdgcn_sched_barrier(0);
    {
        float inv = 1.0f / l;
        _Float16* ow = (_Float16*)lds + (size_t)l31 * 72;
#pragma unroll
        for (int rr = 0; rr < 4; ++rr) {
            h4 a, b;
#pragma unroll
            for (int q = 0; q < 4; ++q) {
                a[q] = (_Float16)(O0[rr * 4 + q] * inv);
                b[q] = (_Float16)(O1[rr * 4 + q] * inv);
            }
            *(h4*)(&ow[rr * 8 + h4o]) = a;
            *(h4*)(&ow[32 + rr * 8 + h4o]) = b;
        }
    }
    asm volatile("s_waitcnt lgkmcnt(0)" ::: "memory");
    __builtin_amdgcn_sched_barrier(0);
    {
        const int b = bh >> 4, head = bh & 15;
        const int row = t >> 1;
#pragma unroll
        for (int i = 0; i < 4; ++i) {
            int seg = (t & 1) * 4 + i;
            h8 v = *(const h8*)(&lds[row * 72 + seg * 8]);
            *(h8*)(Yh + ((size_t)(b * 2048 + qb * 32 + row)) * 1024 + head * 64 + seg * 8) = v;
        }
    }
}

extern "C" void kernel_launch(void* const* d_in, const int* in_sizes, int n_in,
                              void* d_out, int out_size, void* d_ws, size_t ws_size,
                              hipStream_t stream) {
    const float* x  = (const float*)d_in[0];
    const float* Wa = (const float*)d_in[1];
    const float* ba = (const float*)d_in[2];
    const float* Wp = (const float*)d_in[3];
    const float* bp = (const float*)d_in[4];
    float* out = (float*)d_out;

    _Float16* ws = (_Float16*)d_ws;
    const size_t SZ_X = (size_t)8192 * 1024;
    const size_t SZ_WA = (size_t)3072 * 1024;
    const size_t SZ_WP = (size_t)1024 * 1024;
    const size_t SZ_H = (size_t)64 * 2048 * 64;
    _Float16* xh  = ws;
    _Float16* WaT = xh + SZ_X;
    _Float16* WpT = WaT + SZ_WA;
    _Float16* Qh  = WpT + SZ_WP;
    _Float16* Kh  = Qh + SZ_H;
    _Float16* Vth = Kh + SZ_H;    // V transposed: (bh, d, t)
    _Float16* Yh  = Vth + SZ_H;

    k_f32_to_f16<<<8192, 256, 0, stream>>>(x, xh, (int)(SZ_X / 4));
    k_transpose_f16<<<dim3(16, 48), 256, 0, stream>>>(Wa, WaT, 1024, 3072);
    k_transpose_f16<<<dim3(16, 16), 256, 0, stream>>>(Wp, WpT, 1024, 1024);
    k_gemm<0><<<dim3(64, 24), 256, 0, stream>>>(xh, WaT, ba, Qh, Kh, Vth, nullptr,
                                                8192, 3072, 1024);
    k_attn<<<4096, 64, 0, stream>>>(Qh, Kh, Vth, Yh);
    k_gemm<1><<<dim3(64, 8), 256, 0, stream>>>(Yh, WpT, bp, nullptr, nullptr, nullptr,
                                               out, 8192, 1024, 1024);
}

// Round 6
// 196.805 us; speedup vs baseline: 1.9746x; 1.0056x over previous
//
#include <hip/hip_runtime.h>

typedef __attribute__((ext_vector_type(8))) _Float16 h8;
typedef __attribute__((ext_vector_type(4))) _Float16 h4;
typedef __attribute__((ext_vector_type(4))) float f4;
typedef __attribute__((ext_vector_type(16))) float f16x;
typedef __attribute__((ext_vector_type(4))) unsigned u4;

#define MFMA16(a,b,c) __builtin_amdgcn_mfma_f32_16x16x32_f16(a,b,c,0,0,0)
#define MFMA32(a,b,c) __builtin_amdgcn_mfma_f32_32x32x16_f16(a,b,c,0,0,0)

// async global->LDS, 16B per lane; LDS dest = wave-uniform base + lane*16
__device__ inline void gload16(const void* g, void* l) {
    __builtin_amdgcn_global_load_lds(
        (const __attribute__((address_space(1))) void*)g,
        (__attribute__((address_space(3))) void*)l, 16, 0, 0);
}

// partner-half (lane ^ 32) value, semantics-guaranteed
__device__ inline float swap_half(float x) { return __shfl_xor(x, 32, 64); }

// ---------------- fp32 -> f16 elementwise (vectorized) ----------------
__global__ __launch_bounds__(256) void k_f32_to_f16(const float* __restrict__ in,
                                                    _Float16* __restrict__ out, int n4) {
    int i = blockIdx.x * 256 + threadIdx.x;
    if (i < n4) {
        float4 v = ((const float4*)in)[i];
        h4 h;
        h[0] = (_Float16)v.x; h[1] = (_Float16)v.y;
        h[2] = (_Float16)v.z; h[3] = (_Float16)v.w;
        ((h4*)out)[i] = h;
    }
}

// ---------------- fp32 (K,N) -> f16 (N,K) tiled transpose ----------------
__global__ __launch_bounds__(256) void k_transpose_f16(const float* __restrict__ W,
                                                       _Float16* __restrict__ Wt,
                                                       int K, int N) {
    __shared__ float tile[64 * 68];
    const int k0 = blockIdx.x * 64, n0 = blockIdx.y * 64;
    const int t = threadIdx.x;
    const int tr = t >> 4;
    const int tc = t & 15;
#pragma unroll
    for (int i = 0; i < 4; ++i) {
        int r = tr + i * 16;
        float4 v = *(const float4*)(W + (size_t)(k0 + r) * N + n0 + tc * 4);
        *(float4*)(&tile[r * 68 + tc * 4]) = v;
    }
    __syncthreads();
#pragma unroll
    for (int i = 0; i < 4; ++i) {
        int nl = tr + i * 16;
        h4 hv;
#pragma unroll
        for (int j = 0; j < 4; ++j)
            hv[j] = (_Float16)tile[(tc * 4 + j) * 68 + nl];
        *(h4*)(Wt + (size_t)(n0 + nl) * K + k0 + tc * 4) = hv;
    }
}

// ---------------- 128x128 MFMA GEMM (m97 structure: global_load_lds staging) ----------------
// MODE 0: scatter into Q/K (B,H,T,64) and V^T (B,H,64,T) f16 buffers;
//         Q pre-scaled by 0.125*log2(e) (attention works in exp2 domain).
// MODE 1: fp32 out.
template <int MODE>
__global__ __launch_bounds__(256) void k_gemm(const _Float16* __restrict__ A,
                                              const _Float16* __restrict__ Bt,
                                              const float* __restrict__ bias,
                                              _Float16* __restrict__ oQ,
                                              _Float16* __restrict__ oK,
                                              _Float16* __restrict__ oV,
                                              float* __restrict__ oF,
                                              int M, int N, int K) {
    __shared__ _Float16 As[128 * 32];   // linear [row][k], 64B rows (gload_lds needs linear dest)
    __shared__ _Float16 Bs[128 * 32];
    const int tid = threadIdx.x;
    const int lane = tid & 63, wv = tid >> 6;
    const int wm = wv >> 1, wn = wv & 1;
    const int l15 = lane & 15, l4 = lane >> 4;
    const int bm = blockIdx.x * 128, bn = blockIdx.y * 128;
    f4 acc[4][4] = {};

    // staging geometry: wave wv, instr j covers rows (wv*2+j)*16 .. +15
    const int srow = lane >> 2, scol = (lane & 3) * 8;
    const _Float16* Ag = A + (size_t)(bm + srow) * K + scol;
    const _Float16* Bg = Bt + (size_t)(bn + srow) * K + scol;

    for (int k0 = 0; k0 < K; k0 += 32) {
#pragma unroll
        for (int j = 0; j < 2; ++j) {
            const int rb_ = (wv * 2 + j) * 16;
            gload16(Ag + (size_t)rb_ * K + k0, &As[(wv * 2 + j) * 512]);
            gload16(Bg + (size_t)rb_ * K + k0, &Bs[(wv * 2 + j) * 512]);
        }
        asm volatile("s_waitcnt vmcnt(0)" ::: "memory");
        __syncthreads();

        h8 af[4], bf[4];
#pragma unroll
        for (int i = 0; i < 4; ++i)
            af[i] = *(const h8*)(&As[(wm * 64 + i * 16 + l15) * 32 + l4 * 8]);
#pragma unroll
        for (int i = 0; i < 4; ++i)
            bf[i] = *(const h8*)(&Bs[(wn * 64 + i * 16 + l15) * 32 + l4 * 8]);
#pragma unroll
        for (int mi = 0; mi < 4; ++mi)
#pragma unroll
            for (int ni = 0; ni < 4; ++ni)
                acc[mi][ni] = MFMA16(af[mi], bf[ni], acc[mi][ni]);
        __syncthreads();
    }

#pragma unroll
    for (int mi = 0; mi < 4; ++mi) {
#pragma unroll
        for (int ni = 0; ni < 4; ++ni) {
            int col = bn + wn * 64 + ni * 16 + l15;
            float bv = bias[col];
            int rb = bm + wm * 64 + mi * 16 + l4 * 4;
            if (MODE == 0) {
                int which = col >> 10, n1 = col & 1023;
                int hh = n1 >> 6, dd = n1 & 63;
                if (which == 2) {
                    int b = rb >> 11, tq = rb & 2047;
                    h4 pv;
#pragma unroll
                    for (int i = 0; i < 4; ++i) pv[i] = (_Float16)(acc[mi][ni][i] + bv);
                    *(h4*)(oV + ((size_t)(b * 16 + hh) * 64 + dd) * 2048 + tq) = pv;
                } else {
                    _Float16* dst = which == 0 ? oQ : oK;
                    const float scl = which == 0 ? 0.18033688011112042f : 1.0f; // 0.125*log2(e)
#pragma unroll
                    for (int i = 0; i < 4; ++i) {
                        int row = rb + i;
                        int b = row >> 11, tq = row & 2047;
                        dst[(((size_t)b * 16 + hh) * 2048 + tq) * 64 + dd] =
                            (_Float16)((acc[mi][ni][i] + bv) * scl);
                    }
                }
            } else {
#pragma unroll
                for (int i = 0; i < 4; ++i)
                    oF[(size_t)(rb + i) * N + col] = acc[mi][ni][i] + bv;
            }
        }
    }
}

// ---------------- causal flash attention: 1 wave / 32 q-rows per block ----------------
// No barriers (wave-private LDS, DS in-order). Swapped-operand 32x32 MFMA,
// lane-local softmax in exp2 domain, T13 defer-rescale, T14 reg-staged prefetch.
// LDS byte-swizzle for K/V tiles (row stride 128B): cb ^= (row&7)<<4.
#define SWZI(row, cb) ((((row) << 7) + ((cb) ^ ((((row) & 7) << 4)))) >> 1)

__global__ __launch_bounds__(64) void k_attn(const _Float16* __restrict__ Qh,
                                             const _Float16* __restrict__ Kh,
                                             const _Float16* __restrict__ Vt,
                                             _Float16* __restrict__ Yh) {
    __shared__ _Float16 lds[8192];         // [0..4095]=K tile, [4096..]=V tile; reused in epilogue
    const int bid = blockIdx.x;
    const int bh = bid & 63;               // consecutive bids -> different bh -> XCD-local K/V
    const int qb = 63 - (bid >> 6);        // long q-tiles dispatched first
    const int t = threadIdx.x;
    const int l31 = t & 31, hi = t >> 5;
    const int h16 = hi * 16, h4o = hi * 4;
    const size_t base = (size_t)bh * 2048 * 64;

    const int qabs = qb * 32 + l31;
    h8 qf[4];
#pragma unroll
    for (int dk = 0; dk < 4; ++dk)
        qf[dk] = *(const h8*)(Qh + base + (size_t)qabs * 64 + dk * 16 + hi * 8);

    f16x O0 = {}, O1 = {};
    float m = -1e30f, l = 0.f;

    // staging geometry: instr j covers rows j*8..j*8+7, 8 lanes x 16B per row
    const int sr = t >> 3;                 // row-in-octet 0..7
    const int sc = (t & 7) * 8;            // element col base
    const _Float16* Kg = Kh + base + (size_t)sr * 64 + sc;
    const _Float16* Vg = Vt + base + (size_t)sr * 2048 + sc;
    const int kbw = qb >> 1;               // wave's last key tile

    // prologue: stage tile 0
    {
        h8 kn[8], vn[8];
#pragma unroll
        for (int j = 0; j < 8; ++j) kn[j] = *(const h8*)(Kg + j * 512);
#pragma unroll
        for (int j = 0; j < 8; ++j) vn[j] = *(const h8*)(Vg + j * 16384);
#pragma unroll
        for (int j = 0; j < 8; ++j) *(h8*)(&lds[SWZI(j * 8 + sr, (t & 7) * 16)]) = kn[j];
#pragma unroll
        for (int j = 0; j < 8; ++j) *(h8*)(&lds[4096 + SWZI(j * 8 + sr, (t & 7) * 16)]) = vn[j];
    }
    asm volatile("s_waitcnt lgkmcnt(0)" ::: "memory");
    __builtin_amdgcn_sched_barrier(0);

    for (int kb = 0; kb <= kbw; ++kb) {
        const bool pre = (kb < kbw);
        h8 kn[8], vn[8];
        if (pre) {  // T14: issue next K tile early
#pragma unroll
            for (int j = 0; j < 8; ++j)
                kn[j] = *(const h8*)(Kg + (size_t)(kb + 1) * 4096 + j * 512);
        }

        // ---- QK^T swapped: S^T[key][q], lane=q, regs=keys (log2 domain) ----
        f16x S0 = {}, S1 = {};
        __builtin_amdgcn_s_setprio(1);
#pragma unroll
        for (int dk = 0; dk < 4; ++dk) {
            h8 kf0 = *(const h8*)(&lds[SWZI(l31, dk * 32 + h16)]);
            h8 kf1 = *(const h8*)(&lds[SWZI(32 + l31, dk * 32 + h16)]);
            S0 = MFMA32(kf0, qf[dk], S0);
            S1 = MFMA32(kf1, qf[dk], S1);
        }
        __builtin_amdgcn_s_setprio(0);

        if (pre) {  // issue next V tile; latency hides under softmax
#pragma unroll
            for (int j = 0; j < 8; ++j)
                vn[j] = *(const h8*)(Vg + (size_t)(kb + 1) * 64 + j * 16384);
        }

        // ---- causal mask (final tile only) ----
        if (kb == kbw) {
#pragma unroll
            for (int r = 0; r < 16; ++r) {
                int key = kb * 64 + (r & 3) + 8 * (r >> 2) + h4o;
                if (key > qabs) S0[r] = -1e30f;
                if (key + 32 > qabs) S1[r] = -1e30f;
            }
        }

        // ---- in-register online softmax (exp2 domain, T13 defer-rescale) ----
        float tr[16];
#pragma unroll
        for (int r = 0; r < 16; ++r) tr[r] = fmaxf(S0[r], S1[r]);
#pragma unroll
        for (int st = 8; st >= 1; st >>= 1)
#pragma unroll
            for (int r = 0; r < st; ++r) tr[r] = fmaxf(tr[r], tr[r + st]);
        float pm = fmaxf(tr[0], swap_half(tr[0]));
        if (!__all(pm - m <= 8.f)) {       // rescale only when max really grew
            float mnew = fmaxf(m, pm);
            float scl = __builtin_amdgcn_exp2f(m - mnew);
            m = mnew;
            l *= scl;
#pragma unroll
            for (int r = 0; r < 16; ++r) { O0[r] *= scl; O1[r] *= scl; }
        }
#pragma unroll
        for (int r = 0; r < 16; ++r) {
            S0[r] = __builtin_amdgcn_exp2f(S0[r] - m);
            S1[r] = __builtin_amdgcn_exp2f(S1[r] - m);
        }
#pragma unroll
        for (int r = 0; r < 16; ++r) tr[r] = S0[r] + S1[r];
#pragma unroll
        for (int st = 8; st >= 1; st >>= 1)
#pragma unroll
            for (int r = 0; r < st; ++r) tr[r] += tr[r + st];
        l += tr[0] + swap_half(tr[0]);

        // ---- T12: pack P into PV B-frags (word exchange via shfl_xor 32) ----
        h8 pb[4];
#pragma unroll
        for (int kk = 0; kk < 4; ++kk) {
            const int bb = (kk & 1) * 8;
            unsigned W0, W1, W2, W3;
            if (kk < 2) {
                W0 = __builtin_bit_cast(unsigned, __builtin_amdgcn_cvt_pkrtz(S0[bb + 0], S0[bb + 1]));
                W1 = __builtin_bit_cast(unsigned, __builtin_amdgcn_cvt_pkrtz(S0[bb + 2], S0[bb + 3]));
                W2 = __builtin_bit_cast(unsigned, __builtin_amdgcn_cvt_pkrtz(S0[bb + 4], S0[bb + 5]));
                W3 = __builtin_bit_cast(unsigned, __builtin_amdgcn_cvt_pkrtz(S0[bb + 6], S0[bb + 7]));
            } else {
                W0 = __builtin_bit_cast(unsigned, __builtin_amdgcn_cvt_pkrtz(S1[bb + 0], S1[bb + 1]));
                W1 = __builtin_bit_cast(unsigned, __builtin_amdgcn_cvt_pkrtz(S1[bb + 2], S1[bb + 3]));
                W2 = __builtin_bit_cast(unsigned, __builtin_amdgcn_cvt_pkrtz(S1[bb + 4], S1[bb + 5]));
                W3 = __builtin_bit_cast(unsigned, __builtin_amdgcn_cvt_pkrtz(S1[bb + 6], S1[bb + 7]));
            }
            unsigned E0 = (unsigned)__shfl_xor((int)(hi ? W0 : W2), 32, 64);
            unsigned E1 = (unsigned)__shfl_xor((int)(hi ? W1 : W3), 32, 64);
            u4 wvv;
            wvv[0] = hi ? E0 : W0;
            wvv[1] = hi ? E1 : W1;
            wvv[2] = hi ? W2 : E0;
            wvv[3] = hi ? W3 : E1;
            pb[kk] = __builtin_bit_cast(h8, wvv);
        }

        // ---- PV swapped: O^T[d][q] += V^T-frag x P-frag ----
        __builtin_amdgcn_s_setprio(1);
#pragma unroll
        for (int kk = 0; kk < 4; ++kk) {
            h8 vf0 = *(const h8*)(&lds[4096 + SWZI(l31, kk * 32 + h16)]);
            h8 vf1 = *(const h8*)(&lds[4096 + SWZI(32 + l31, kk * 32 + h16)]);
            O0 = MFMA32(vf0, pb[kk], O0);
            O1 = MFMA32(vf1, pb[kk], O1);
        }
        __builtin_amdgcn_s_setprio(0);

        if (pre) {  // write next tile (DS in-order per wave; all frag reads already issued)
            asm volatile("s_waitcnt lgkmcnt(0)" ::: "memory");
            __builtin_amdgcn_sched_barrier(0);
#pragma unroll
            for (int j = 0; j < 8; ++j) *(h8*)(&lds[SWZI(j * 8 + sr, (t & 7) * 16)]) = kn[j];
#pragma unroll
            for (int j = 0; j < 8; ++j) *(h8*)(&lds[4096 + SWZI(j * 8 + sr, (t & 7) * 16)]) = vn[j];
        }
    }

    // ---- epilogue: O^T (lane=q, regs=d) -> LDS (reuse K area) -> coalesced global ----
    asm volatile("s_waitcnt lgkmcnt(0)" ::: "memory");
    __builtin_amdgcn_sched_barrier(0);
    {
        float inv = 1.0f / l;
        _Float16* ow = (_Float16*)lds + (size_t)l31 * 72;
#pragma unroll
        for (int rr = 0; rr < 4; ++rr) {
            h4 a, b;
#pragma unroll
            for (int q = 0; q < 4; ++q) {
                a[q] = (_Float16)(O0[rr * 4 + q] * inv);
                b[q] = (_Float16)(O1[rr * 4 + q] * inv);
            }
            *(h4*)(&ow[rr * 8 + h4o]) = a;
            *(h4*)(&ow[32 + rr * 8 + h4o]) = b;
        }
    }
    asm volatile("s_waitcnt lgkmcnt(0)" ::: "memory");
    __builtin_amdgcn_sched_barrier(0);
    {
        const int b = bh >> 4, head = bh & 15;
        const int row = t >> 1;
#pragma unroll
        for (int i = 0; i < 4; ++i) {
            int seg = (t & 1) * 4 + i;
            h8 v = *(const h8*)(&lds[row * 72 + seg * 8]);
            *(h8*)(Yh + ((size_t)(b * 2048 + qb * 32 + row)) * 1024 + head * 64 + seg * 8) = v;
        }
    }
}

extern "C" void kernel_launch(void* const* d_in, const int* in_sizes, int n_in,
                              void* d_out, int out_size, void* d_ws, size_t ws_size,
                              hipStream_t stream) {
    const float* x  = (const float*)d_in[0];
    const float* Wa = (const float*)d_in[1];
    const float* ba = (const float*)d_in[2];
    const float* Wp = (const float*)d_in[3];
    const float* bp = (const float*)d_in[4];
    float* out = (float*)d_out;

    _Float16* ws = (_Float16*)d_ws;
    const size_t SZ_X = (size_t)8192 * 1024;
    const size_t SZ_WA = (size_t)3072 * 1024;
    const size_t SZ_WP = (size_t)1024 * 1024;
    const size_t SZ_H = (size_t)64 * 2048 * 64;
    _Float16* xh  = ws;
    _Float16* WaT = xh + SZ_X;
    _Float16* WpT = WaT + SZ_WA;
    _Float16* Qh  = WpT + SZ_WP;
    _Float16* Kh  = Qh + SZ_H;
    _Float16* Vth = Kh + SZ_H;    // V transposed: (bh, d, t)
    _Float16* Yh  = Vth + SZ_H;

    k_f32_to_f16<<<8192, 256, 0, stream>>>(x, xh, (int)(SZ_X / 4));
    k_transpose_f16<<<dim3(16, 48), 256, 0, stream>>>(Wa, WaT, 1024, 3072);
    k_transpose_f16<<<dim3(16, 16), 256, 0, stream>>>(Wp, WpT, 1024, 1024);
    k_gemm<0><<<dim3(64, 24), 256, 0, stream>>>(xh, WaT, ba, Qh, Kh, Vth, nullptr,
                                                8192, 3072, 1024);
    k_attn<<<4096, 64, 0, stream>>>(Qh, Kh, Vth, Yh);
    k_gemm<1><<<dim3(64, 8), 256, 0, stream>>>(Yh, WpT, bp, nullptr, nullptr, nullptr,
                                               out, 8192, 1024, 1024);
}

// Round 7
// 188.069 us; speedup vs baseline: 2.0663x; 1.0465x over previous
//
#include <hip/hip_runtime.h>

typedef __attribute__((ext_vector_type(8))) _Float16 h8;
typedef __attribute__((ext_vector_type(4))) _Float16 h4;
typedef __attribute__((ext_vector_type(4))) float f4;
typedef __attribute__((ext_vector_type(16))) float f16x;
typedef __attribute__((ext_vector_type(4))) unsigned u4;

#define MFMA16(a,b,c) __builtin_amdgcn_mfma_f32_16x16x32_f16(a,b,c,0,0,0)
#define MFMA32(a,b,c) __builtin_amdgcn_mfma_f32_32x32x16_f16(a,b,c,0,0,0)

// async global->LDS, 16B per lane; LDS dest = wave-uniform base + lane*16
__device__ inline void gload16(const void* g, void* l) {
    __builtin_amdgcn_global_load_lds(
        (const __attribute__((address_space(1))) void*)g,
        (__attribute__((address_space(3))) void*)l, 16, 0, 0);
}

// partner-half (lane ^ 32) value, semantics-guaranteed
__device__ inline float swap_half(float x) { return __shfl_xor(x, 32, 64); }

// ---------------- fp32 -> f16 elementwise (vectorized) ----------------
__global__ __launch_bounds__(256) void k_f32_to_f16(const float* __restrict__ in,
                                                    _Float16* __restrict__ out, int n4) {
    int i = blockIdx.x * 256 + threadIdx.x;
    if (i < n4) {
        float4 v = ((const float4*)in)[i];
        h4 h;
        h[0] = (_Float16)v.x; h[1] = (_Float16)v.y;
        h[2] = (_Float16)v.z; h[3] = (_Float16)v.w;
        ((h4*)out)[i] = h;
    }
}

// ---------------- fp32 (K,N) -> f16 (N,K) tiled transpose ----------------
__global__ __launch_bounds__(256) void k_transpose_f16(const float* __restrict__ W,
                                                       _Float16* __restrict__ Wt,
                                                       int K, int N) {
    __shared__ float tile[64 * 68];
    const int k0 = blockIdx.x * 64, n0 = blockIdx.y * 64;
    const int t = threadIdx.x;
    const int tr = t >> 4;
    const int tc = t & 15;
#pragma unroll
    for (int i = 0; i < 4; ++i) {
        int r = tr + i * 16;
        float4 v = *(const float4*)(W + (size_t)(k0 + r) * N + n0 + tc * 4);
        *(float4*)(&tile[r * 68 + tc * 4]) = v;
    }
    __syncthreads();
#pragma unroll
    for (int i = 0; i < 4; ++i) {
        int nl = tr + i * 16;
        h4 hv;
#pragma unroll
        for (int j = 0; j < 4; ++j)
            hv[j] = (_Float16)tile[(tc * 4 + j) * 68 + nl];
        *(h4*)(Wt + (size_t)(n0 + nl) * K + k0 + tc * 4) = hv;
    }
}

// ---------------- 128x128 MFMA GEMM, 2-phase double-buffered gload_lds ----------------
// T3-minimum schedule: STAGE(next) issued BEFORE compute(cur); one vmcnt(0)+barrier per K-step.
// MODE 0: scatter into Q/K (B,H,T,64) and V^T (B,H,64,T) f16 buffers;
//         Q pre-scaled by 0.125*log2(e) (attention works in exp2 domain).
// MODE 1: fp32 out.
template <int MODE>
__global__ __launch_bounds__(256) void k_gemm(const _Float16* __restrict__ A,
                                              const _Float16* __restrict__ Bt,
                                              const float* __restrict__ bias,
                                              _Float16* __restrict__ oQ,
                                              _Float16* __restrict__ oK,
                                              _Float16* __restrict__ oV,
                                              float* __restrict__ oF,
                                              int M, int N, int K) {
    __shared__ _Float16 As[2][128 * 32];  // linear [row][k], 64B rows (gload_lds: linear dest)
    __shared__ _Float16 Bs[2][128 * 32];
    const int tid = threadIdx.x;
    const int lane = tid & 63, wv = tid >> 6;
    const int wm = wv >> 1, wn = wv & 1;
    const int l15 = lane & 15, l4 = lane >> 4;
    const int bm = blockIdx.x * 128, bn = blockIdx.y * 128;
    f4 acc[4][4] = {};

    // staging geometry: wave wv, instr j covers rows (wv*2+j)*16 .. +15
    const int srow = lane >> 2, scol = (lane & 3) * 8;
    const _Float16* Ag = A + (size_t)(bm + srow) * K + scol;
    const _Float16* Bg = Bt + (size_t)(bn + srow) * K + scol;

    // prologue: stage tile 0 into buf 0
#pragma unroll
    for (int j = 0; j < 2; ++j) {
        const int rb_ = (wv * 2 + j) * 16;
        gload16(Ag + (size_t)rb_ * K, &As[0][(wv * 2 + j) * 512]);
        gload16(Bg + (size_t)rb_ * K, &Bs[0][(wv * 2 + j) * 512]);
    }
    asm volatile("s_waitcnt vmcnt(0)" ::: "memory");
    __syncthreads();

    int cur = 0;
    for (int k0 = 0; k0 < K; k0 += 32) {
        // T3: issue next-tile loads into buf^1 BEFORE compute; they fly under the MFMAs
        if (k0 + 32 < K) {
#pragma unroll
            for (int j = 0; j < 2; ++j) {
                const int rb_ = (wv * 2 + j) * 16;
                gload16(Ag + (size_t)rb_ * K + k0 + 32, &As[cur ^ 1][(wv * 2 + j) * 512]);
                gload16(Bg + (size_t)rb_ * K + k0 + 32, &Bs[cur ^ 1][(wv * 2 + j) * 512]);
            }
        }

        const _Float16* Ac = As[cur];
        const _Float16* Bc = Bs[cur];
        h8 af[4], bf[4];
#pragma unroll
        for (int i = 0; i < 4; ++i)
            af[i] = *(const h8*)(&Ac[(wm * 64 + i * 16 + l15) * 32 + l4 * 8]);
#pragma unroll
        for (int i = 0; i < 4; ++i)
            bf[i] = *(const h8*)(&Bc[(wn * 64 + i * 16 + l15) * 32 + l4 * 8]);
        __builtin_amdgcn_s_setprio(1);
#pragma unroll
        for (int mi = 0; mi < 4; ++mi)
#pragma unroll
            for (int ni = 0; ni < 4; ++ni)
                acc[mi][ni] = MFMA16(af[mi], bf[ni], acc[mi][ni]);
        __builtin_amdgcn_s_setprio(0);

        asm volatile("s_waitcnt vmcnt(0)" ::: "memory");  // next tile resident
        __syncthreads();                                   // all waves done reading cur
        cur ^= 1;
    }

#pragma unroll
    for (int mi = 0; mi < 4; ++mi) {
#pragma unroll
        for (int ni = 0; ni < 4; ++ni) {
            int col = bn + wn * 64 + ni * 16 + l15;
            float bv = bias[col];
            int rb = bm + wm * 64 + mi * 16 + l4 * 4;
            if (MODE == 0) {
                int which = col >> 10, n1 = col & 1023;
                int hh = n1 >> 6, dd = n1 & 63;
                if (which == 2) {
                    int b = rb >> 11, tq = rb & 2047;
                    h4 pv;
#pragma unroll
                    for (int i = 0; i < 4; ++i) pv[i] = (_Float16)(acc[mi][ni][i] + bv);
                    *(h4*)(oV + ((size_t)(b * 16 + hh) * 64 + dd) * 2048 + tq) = pv;
                } else {
                    _Float16* dst = which == 0 ? oQ : oK;
                    const float scl = which == 0 ? 0.18033688011112042f : 1.0f; // 0.125*log2(e)
#pragma unroll
                    for (int i = 0; i < 4; ++i) {
                        int row = rb + i;
                        int b = row >> 11, tq = row & 2047;
                        dst[(((size_t)b * 16 + hh) * 2048 + tq) * 64 + dd] =
                            (_Float16)((acc[mi][ni][i] + bv) * scl);
                    }
                }
            } else {
#pragma unroll
                for (int i = 0; i < 4; ++i)
                    oF[(size_t)(rb + i) * N + col] = acc[mi][ni][i] + bv;
            }
        }
    }
}

// ---------------- causal flash attention: 1 wave / 32 q-rows per block ----------------
// No barriers (wave-private LDS, DS in-order). Swapped-operand 32x32 MFMA,
// lane-local softmax in exp2 domain, T13 defer-rescale, T14 reg-staged prefetch.
// LDS byte-swizzle for K/V tiles (row stride 128B): cb ^= (row&7)<<4.
#define SWZI(row, cb) ((((row) << 7) + ((cb) ^ ((((row) & 7) << 4)))) >> 1)

__global__ __launch_bounds__(64) void k_attn(const _Float16* __restrict__ Qh,
                                             const _Float16* __restrict__ Kh,
                                             const _Float16* __restrict__ Vt,
                                             _Float16* __restrict__ Yh) {
    __shared__ _Float16 lds[8192];         // [0..4095]=K tile, [4096..]=V tile; reused in epilogue
    const int bid = blockIdx.x;
    const int bh = bid & 63;               // consecutive bids -> different bh -> XCD-local K/V
    const int qb = 63 - (bid >> 6);        // long q-tiles dispatched first
    const int t = threadIdx.x;
    const int l31 = t & 31, hi = t >> 5;
    const int h16 = hi * 16, h4o = hi * 4;
    const size_t base = (size_t)bh * 2048 * 64;

    const int qabs = qb * 32 + l31;
    h8 qf[4];
#pragma unroll
    for (int dk = 0; dk < 4; ++dk)
        qf[dk] = *(const h8*)(Qh + base + (size_t)qabs * 64 + dk * 16 + hi * 8);

    f16x O0 = {}, O1 = {};
    float m = -1e30f, l = 0.f;

    // staging geometry: instr j covers rows j*8..j*8+7, 8 lanes x 16B per row
    const int sr = t >> 3;                 // row-in-octet 0..7
    const int sc = (t & 7) * 8;            // element col base
    const _Float16* Kg = Kh + base + (size_t)sr * 64 + sc;
    const _Float16* Vg = Vt + base + (size_t)sr * 2048 + sc;
    const int kbw = qb >> 1;               // wave's last key tile

    // prologue: stage tile 0
    {
        h8 kn[8], vn[8];
#pragma unroll
        for (int j = 0; j < 8; ++j) kn[j] = *(const h8*)(Kg + j * 512);
#pragma unroll
        for (int j = 0; j < 8; ++j) vn[j] = *(const h8*)(Vg + j * 16384);
#pragma unroll
        for (int j = 0; j < 8; ++j) *(h8*)(&lds[SWZI(j * 8 + sr, (t & 7) * 16)]) = kn[j];
#pragma unroll
        for (int j = 0; j < 8; ++j) *(h8*)(&lds[4096 + SWZI(j * 8 + sr, (t & 7) * 16)]) = vn[j];
    }
    asm volatile("s_waitcnt lgkmcnt(0)" ::: "memory");
    __builtin_amdgcn_sched_barrier(0);

    for (int kb = 0; kb <= kbw; ++kb) {
        const bool pre = (kb < kbw);
        h8 kn[8], vn[8];
        if (pre) {  // T14: issue next K tile early
#pragma unroll
            for (int j = 0; j < 8; ++j)
                kn[j] = *(const h8*)(Kg + (size_t)(kb + 1) * 4096 + j * 512);
        }

        // ---- QK^T swapped: S^T[key][q], lane=q, regs=keys (log2 domain) ----
        f16x S0 = {}, S1 = {};
        __builtin_amdgcn_s_setprio(1);
#pragma unroll
        for (int dk = 0; dk < 4; ++dk) {
            h8 kf0 = *(const h8*)(&lds[SWZI(l31, dk * 32 + h16)]);
            h8 kf1 = *(const h8*)(&lds[SWZI(32 + l31, dk * 32 + h16)]);
            S0 = MFMA32(kf0, qf[dk], S0);
            S1 = MFMA32(kf1, qf[dk], S1);
        }
        __builtin_amdgcn_s_setprio(0);

        if (pre) {  // issue next V tile; latency hides under softmax
#pragma unroll
            for (int j = 0; j < 8; ++j)
                vn[j] = *(const h8*)(Vg + (size_t)(kb + 1) * 64 + j * 16384);
        }

        // ---- causal mask (final tile only) ----
        if (kb == kbw) {
#pragma unroll
            for (int r = 0; r < 16; ++r) {
                int key = kb * 64 + (r & 3) + 8 * (r >> 2) + h4o;
                if (key > qabs) S0[r] = -1e30f;
                if (key + 32 > qabs) S1[r] = -1e30f;
            }
        }

        // ---- in-register online softmax (exp2 domain, T13 defer-rescale) ----
        float tr[16];
#pragma unroll
        for (int r = 0; r < 16; ++r) tr[r] = fmaxf(S0[r], S1[r]);
#pragma unroll
        for (int st = 8; st >= 1; st >>= 1)
#pragma unroll
            for (int r = 0; r < st; ++r) tr[r] = fmaxf(tr[r], tr[r + st]);
        float pm = fmaxf(tr[0], swap_half(tr[0]));
        if (!__all(pm - m <= 8.f)) {       // rescale only when max really grew
            float mnew = fmaxf(m, pm);
            float scl = __builtin_amdgcn_exp2f(m - mnew);
            m = mnew;
            l *= scl;
#pragma unroll
            for (int r = 0; r < 16; ++r) { O0[r] *= scl; O1[r] *= scl; }
        }
#pragma unroll
        for (int r = 0; r < 16; ++r) {
            S0[r] = __builtin_amdgcn_exp2f(S0[r] - m);
            S1[r] = __builtin_amdgcn_exp2f(S1[r] - m);
        }
#pragma unroll
        for (int r = 0; r < 16; ++r) tr[r] = S0[r] + S1[r];
#pragma unroll
        for (int st = 8; st >= 1; st >>= 1)
#pragma unroll
            for (int r = 0; r < st; ++r) tr[r] += tr[r + st];
        l += tr[0] + swap_half(tr[0]);

        // ---- T12: pack P into PV B-frags (word exchange via shfl_xor 32) ----
        h8 pb[4];
#pragma unroll
        for (int kk = 0; kk < 4; ++kk) {
            const int bb = (kk & 1) * 8;
            unsigned W0, W1, W2, W3;
            if (kk < 2) {
                W0 = __builtin_bit_cast(unsigned, __builtin_amdgcn_cvt_pkrtz(S0[bb + 0], S0[bb + 1]));
                W1 = __builtin_bit_cast(unsigned, __builtin_amdgcn_cvt_pkrtz(S0[bb + 2], S0[bb + 3]));
                W2 = __builtin_bit_cast(unsigned, __builtin_amdgcn_cvt_pkrtz(S0[bb + 4], S0[bb + 5]));
                W3 = __builtin_bit_cast(unsigned, __builtin_amdgcn_cvt_pkrtz(S0[bb + 6], S0[bb + 7]));
            } else {
                W0 = __builtin_bit_cast(unsigned, __builtin_amdgcn_cvt_pkrtz(S1[bb + 0], S1[bb + 1]));
                W1 = __builtin_bit_cast(unsigned, __builtin_amdgcn_cvt_pkrtz(S1[bb + 2], S1[bb + 3]));
                W2 = __builtin_bit_cast(unsigned, __builtin_amdgcn_cvt_pkrtz(S1[bb + 4], S1[bb + 5]));
                W3 = __builtin_bit_cast(unsigned, __builtin_amdgcn_cvt_pkrtz(S1[bb + 6], S1[bb + 7]));
            }
            unsigned E0 = (unsigned)__shfl_xor((int)(hi ? W0 : W2), 32, 64);
            unsigned E1 = (unsigned)__shfl_xor((int)(hi ? W1 : W3), 32, 64);
            u4 wvv;
            wvv[0] = hi ? E0 : W0;
            wvv[1] = hi ? E1 : W1;
            wvv[2] = hi ? W2 : E0;
            wvv[3] = hi ? W3 : E1;
            pb[kk] = __builtin_bit_cast(h8, wvv);
        }

        // ---- PV swapped: O^T[d][q] += V^T-frag x P-frag ----
        __builtin_amdgcn_s_setprio(1);
#pragma unroll
        for (int kk = 0; kk < 4; ++kk) {
            h8 vf0 = *(const h8*)(&lds[4096 + SWZI(l31, kk * 32 + h16)]);
            h8 vf1 = *(const h8*)(&lds[4096 + SWZI(32 + l31, kk * 32 + h16)]);
            O0 = MFMA32(vf0, pb[kk], O0);
            O1 = MFMA32(vf1, pb[kk], O1);
        }
        __builtin_amdgcn_s_setprio(0);

        if (pre) {  // write next tile (DS in-order per wave; all frag reads already issued)
            asm volatile("s_waitcnt lgkmcnt(0)" ::: "memory");
            __builtin_amdgcn_sched_barrier(0);
#pragma unroll
            for (int j = 0; j < 8; ++j) *(h8*)(&lds[SWZI(j * 8 + sr, (t & 7) * 16)]) = kn[j];
#pragma unroll
            for (int j = 0; j < 8; ++j) *(h8*)(&lds[4096 + SWZI(j * 8 + sr, (t & 7) * 16)]) = vn[j];
        }
    }

    // ---- epilogue: O^T (lane=q, regs=d) -> LDS (reuse K area) -> coalesced global ----
    asm volatile("s_waitcnt lgkmcnt(0)" ::: "memory");
    __builtin_amdgcn_sched_barrier(0);
    {
        float inv = 1.0f / l;
        _Float16* ow = (_Float16*)lds + (size_t)l31 * 72;
#pragma unroll
        for (int rr = 0; rr < 4; ++rr) {
            h4 a, b;
#pragma unroll
            for (int q = 0; q < 4; ++q) {
                a[q] = (_Float16)(O0[rr * 4 + q] * inv);
                b[q] = (_Float16)(O1[rr * 4 + q] * inv);
            }
            *(h4*)(&ow[rr * 8 + h4o]) = a;
            *(h4*)(&ow[32 + rr * 8 + h4o]) = b;
        }
    }
    asm volatile("s_waitcnt lgkmcnt(0)" ::: "memory");
    __builtin_amdgcn_sched_barrier(0);
    {
        const int b = bh >> 4, head = bh & 15;
        const int row = t >> 1;
#pragma unroll
        for (int i = 0; i < 4; ++i) {
            int seg = (t & 1) * 4 + i;
            h8 v = *(const h8*)(&lds[row * 72 + seg * 8]);
            *(h8*)(Yh + ((size_t)(b * 2048 + qb * 32 + row)) * 1024 + head * 64 + seg * 8) = v;
        }
    }
}

extern "C" void kernel_launch(void* const* d_in, const int* in_sizes, int n_in,
                              void* d_out, int out_size, void* d_ws, size_t ws_size,
                              hipStream_t stream) {
    const float* x  = (const float*)d_in[0];
    const float* Wa = (const float*)d_in[1];
    const float* ba = (const float*)d_in[2];
    const float* Wp = (const float*)d_in[3];
    const float* bp = (const float*)d_in[4];
    float* out = (float*)d_out;

    _Float16* ws = (_Float16*)d_ws;
    const size_t SZ_X = (size_t)8192 * 1024;
    const size_t SZ_WA = (size_t)3072 * 1024;
    const size_t SZ_WP = (size_t)1024 * 1024;
    const size_t SZ_H = (size_t)64 * 2048 * 64;
    _Float16* xh  = ws;
    _Float16* WaT = xh + SZ_X;
    _Float16* WpT = WaT + SZ_WA;
    _Float16* Qh  = WpT + SZ_WP;
    _Float16* Kh  = Qh + SZ_H;
    _Float16* Vth = Kh + SZ_H;    // V transposed: (bh, d, t)
    _Float16* Yh  = Vth + SZ_H;

    k_f32_to_f16<<<8192, 256, 0, stream>>>(x, xh, (int)(SZ_X / 4));
    k_transpose_f16<<<dim3(16, 48), 256, 0, stream>>>(Wa, WaT, 1024, 3072);
    k_transpose_f16<<<dim3(16, 16), 256, 0, stream>>>(Wp, WpT, 1024, 1024);
    k_gemm<0><<<dim3(64, 24), 256, 0, stream>>>(xh, WaT, ba, Qh, Kh, Vth, nullptr,
                                                8192, 3072, 1024);
    k_attn<<<4096, 64, 0, stream>>>(Qh, Kh, Vth, Yh);
    k_gemm<1><<<dim3(64, 8), 256, 0, stream>>>(Yh, WpT, bp, nullptr, nullptr, nullptr,
                                               out, 8192, 1024, 1024);
}

// Round 8
// 181.548 us; speedup vs baseline: 2.1405x; 1.0359x over previous
//
#include <hip/hip_runtime.h>

typedef __attribute__((ext_vector_type(8))) _Float16 h8;
typedef __attribute__((ext_vector_type(4))) _Float16 h4;
typedef __attribute__((ext_vector_type(4))) float f4;
typedef __attribute__((ext_vector_type(16))) float f16x;
typedef __attribute__((ext_vector_type(4))) unsigned u4;

#define MFMA16(a,b,c) __builtin_amdgcn_mfma_f32_16x16x32_f16(a,b,c,0,0,0)
#define MFMA32(a,b,c) __builtin_amdgcn_mfma_f32_32x32x16_f16(a,b,c,0,0,0)

// async global->LDS, 16B per lane; LDS dest = wave-uniform base + lane*16
__device__ inline void gload16(const void* g, void* l) {
    __builtin_amdgcn_global_load_lds(
        (const __attribute__((address_space(1))) void*)g,
        (__attribute__((address_space(3))) void*)l, 16, 0, 0);
}

// partner-half (lane ^ 32) value, semantics-guaranteed
__device__ inline float swap_half(float x) { return __shfl_xor(x, 32, 64); }

// ---------------- fp32 -> f16 elementwise (vectorized) ----------------
__global__ __launch_bounds__(256) void k_f32_to_f16(const float* __restrict__ in,
                                                    _Float16* __restrict__ out, int n4) {
    int i = blockIdx.x * 256 + threadIdx.x;
    if (i < n4) {
        float4 v = ((const float4*)in)[i];
        h4 h;
        h[0] = (_Float16)v.x; h[1] = (_Float16)v.y;
        h[2] = (_Float16)v.z; h[3] = (_Float16)v.w;
        ((h4*)out)[i] = h;
    }
}

// ---------------- fp32 (K,N) -> f16 (N,K) tiled transpose ----------------
__global__ __launch_bounds__(256) void k_transpose_f16(const float* __restrict__ W,
                                                       _Float16* __restrict__ Wt,
                                                       int K, int N) {
    __shared__ float tile[64 * 68];
    const int k0 = blockIdx.x * 64, n0 = blockIdx.y * 64;
    const int t = threadIdx.x;
    const int tr = t >> 4;
    const int tc = t & 15;
#pragma unroll
    for (int i = 0; i < 4; ++i) {
        int r = tr + i * 16;
        float4 v = *(const float4*)(W + (size_t)(k0 + r) * N + n0 + tc * 4);
        *(float4*)(&tile[r * 68 + tc * 4]) = v;
    }
    __syncthreads();
#pragma unroll
    for (int i = 0; i < 4; ++i) {
        int nl = tr + i * 16;
        h4 hv;
#pragma unroll
        for (int j = 0; j < 4; ++j)
            hv[j] = (_Float16)tile[(tc * 4 + j) * 68 + nl];
        *(h4*)(Wt + (size_t)(n0 + nl) * K + k0 + tc * 4) = hv;
    }
}

// ---------------- 128x128 MFMA GEMM, 2-phase double-buffered gload_lds ----------------
// MODE 0: scatter into Q/K (B,H,T,64) and V^T (B,H,64,T) f16 buffers;
//         Q pre-scaled by 0.125*log2(e) (attention works in exp2 domain).
// MODE 1: fp32 out.
template <int MODE>
__global__ __launch_bounds__(256) void k_gemm(const _Float16* __restrict__ A,
                                              const _Float16* __restrict__ Bt,
                                              const float* __restrict__ bias,
                                              _Float16* __restrict__ oQ,
                                              _Float16* __restrict__ oK,
                                              _Float16* __restrict__ oV,
                                              float* __restrict__ oF,
                                              int M, int N, int K) {
    __shared__ _Float16 As[2][128 * 32];  // linear [row][k], 64B rows (gload_lds: linear dest)
    __shared__ _Float16 Bs[2][128 * 32];
    const int tid = threadIdx.x;
    const int lane = tid & 63, wv = tid >> 6;
    const int wm = wv >> 1, wn = wv & 1;
    const int l15 = lane & 15, l4 = lane >> 4;
    const int bm = blockIdx.x * 128, bn = blockIdx.y * 128;
    f4 acc[4][4] = {};

    const int srow = lane >> 2, scol = (lane & 3) * 8;
    const _Float16* Ag = A + (size_t)(bm + srow) * K + scol;
    const _Float16* Bg = Bt + (size_t)(bn + srow) * K + scol;

#pragma unroll
    for (int j = 0; j < 2; ++j) {
        const int rb_ = (wv * 2 + j) * 16;
        gload16(Ag + (size_t)rb_ * K, &As[0][(wv * 2 + j) * 512]);
        gload16(Bg + (size_t)rb_ * K, &Bs[0][(wv * 2 + j) * 512]);
    }
    asm volatile("s_waitcnt vmcnt(0)" ::: "memory");
    __syncthreads();

    int cur = 0;
    for (int k0 = 0; k0 < K; k0 += 32) {
        if (k0 + 32 < K) {
#pragma unroll
            for (int j = 0; j < 2; ++j) {
                const int rb_ = (wv * 2 + j) * 16;
                gload16(Ag + (size_t)rb_ * K + k0 + 32, &As[cur ^ 1][(wv * 2 + j) * 512]);
                gload16(Bg + (size_t)rb_ * K + k0 + 32, &Bs[cur ^ 1][(wv * 2 + j) * 512]);
            }
        }

        const _Float16* Ac = As[cur];
        const _Float16* Bc = Bs[cur];
        h8 af[4], bf[4];
#pragma unroll
        for (int i = 0; i < 4; ++i)
            af[i] = *(const h8*)(&Ac[(wm * 64 + i * 16 + l15) * 32 + l4 * 8]);
#pragma unroll
        for (int i = 0; i < 4; ++i)
            bf[i] = *(const h8*)(&Bc[(wn * 64 + i * 16 + l15) * 32 + l4 * 8]);
        __builtin_amdgcn_s_setprio(1);
#pragma unroll
        for (int mi = 0; mi < 4; ++mi)
#pragma unroll
            for (int ni = 0; ni < 4; ++ni)
                acc[mi][ni] = MFMA16(af[mi], bf[ni], acc[mi][ni]);
        __builtin_amdgcn_s_setprio(0);

        asm volatile("s_waitcnt vmcnt(0)" ::: "memory");
        __syncthreads();
        cur ^= 1;
    }

#pragma unroll
    for (int mi = 0; mi < 4; ++mi) {
#pragma unroll
        for (int ni = 0; ni < 4; ++ni) {
            int col = bn + wn * 64 + ni * 16 + l15;
            float bv = bias[col];
            int rb = bm + wm * 64 + mi * 16 + l4 * 4;
            if (MODE == 0) {
                int which = col >> 10, n1 = col & 1023;
                int hh = n1 >> 6, dd = n1 & 63;
                if (which == 2) {
                    int b = rb >> 11, tq = rb & 2047;
                    h4 pv;
#pragma unroll
                    for (int i = 0; i < 4; ++i) pv[i] = (_Float16)(acc[mi][ni][i] + bv);
                    *(h4*)(oV + ((size_t)(b * 16 + hh) * 64 + dd) * 2048 + tq) = pv;
                } else {
                    _Float16* dst = which == 0 ? oQ : oK;
                    const float scl = which == 0 ? 0.18033688011112042f : 1.0f; // 0.125*log2(e)
#pragma unroll
                    for (int i = 0; i < 4; ++i) {
                        int row = rb + i;
                        int b = row >> 11, tq = row & 2047;
                        dst[(((size_t)b * 16 + hh) * 2048 + tq) * 64 + dd] =
                            (_Float16)((acc[mi][ni][i] + bv) * scl);
                    }
                }
            } else {
#pragma unroll
                for (int i = 0; i < 4; ++i)
                    oF[(size_t)(rb + i) * N + col] = acc[mi][ni][i] + bv;
            }
        }
    }
}

// ---------------- causal flash attention: 4 waves x 32 q-rows, shared 64-key K/V tile ----------------
// Swapped-operand 32x32 MFMA, lane-local softmax (exp2 domain, T13), shared-LDS staging
// split across 256 threads (4 loads/thread/tile), 2 barriers per tile.
// LDS byte-swizzle (row stride 128B): cb ^= (row&7)<<4.
#define SWZI(row, cb) ((((row) << 7) + ((cb) ^ ((((row) & 7) << 4)))) >> 1)

__global__ __launch_bounds__(256) void k_attn(const _Float16* __restrict__ Qh,
                                              const _Float16* __restrict__ Kh,
                                              const _Float16* __restrict__ Vt,
                                              _Float16* __restrict__ Yh) {
    __shared__ _Float16 lds[8192];         // [0..4095]=K tile, [4096..]=V^T tile; epilogue reuses all
    const int bid = blockIdx.x;
    const int bh = bid & 63;               // consecutive bids -> different bh; same bh -> same XCD slot
    const int qt = 15 - (bid >> 6);        // long q-tiles dispatched first
    const int tid = threadIdx.x, w = tid >> 6;
    const int l31 = tid & 31, hi = (tid >> 5) & 1;
    const int h16 = hi * 16, h4o = hi * 4;
    const size_t base = (size_t)bh * 2048 * 64;

    const int qabs = qt * 128 + w * 32 + l31;
    h8 qf[4];
#pragma unroll
    for (int dk = 0; dk < 4; ++dk)
        qf[dk] = *(const h8*)(Qh + base + (size_t)qabs * 64 + dk * 16 + hi * 8);

    f16x O0 = {}, O1 = {};
    float m = -1e30f, l = 0.f;

    // staging: 256 threads cover 64 rows x 128B in 2 instrs; thread -> (row j*32+sr, 16B seg)
    const int sr = tid >> 3;               // 0..31
    const int sc8 = (tid & 7) * 8;         // f16 col
    const int scb = (tid & 7) * 16;        // byte col
    const int kbb = 2 * qt + 1;            // block's last tile
    const int kbw = 2 * qt + (w >> 1);     // this wave's last tile

    // prologue: stage tile 0
    {
#pragma unroll
        for (int j = 0; j < 2; ++j) {
            int row = j * 32 + sr;
            h8 kv = *(const h8*)(Kh + base + (size_t)row * 64 + sc8);
            h8 vv = *(const h8*)(Vt + base + (size_t)row * 2048 + sc8);
            *(h8*)(&lds[SWZI(row, scb)]) = kv;
            *(h8*)(&lds[4096 + SWZI(row, scb)]) = vv;
        }
    }
    __syncthreads();

    for (int kb = 0; kb <= kbb; ++kb) {
        const bool pre = (kb < kbb);
        h8 kn[2], vn[2];
        if (pre) {  // T14: issue next-tile loads early; written after barrier 1
#pragma unroll
            for (int j = 0; j < 2; ++j) {
                int row = j * 32 + sr;
                kn[j] = *(const h8*)(Kh + base + (size_t)((kb + 1) * 64 + row) * 64 + sc8);
                vn[j] = *(const h8*)(Vt + base + (size_t)row * 2048 + (kb + 1) * 64 + sc8);
            }
        }

        if (kb <= kbw) {
            // ---- QK^T swapped: S^T[key][q], lane=q, regs=keys (log2 domain) ----
            f16x S0 = {}, S1 = {};
            __builtin_amdgcn_s_setprio(1);
#pragma unroll
            for (int dk = 0; dk < 4; ++dk) {
                h8 kf0 = *(const h8*)(&lds[SWZI(l31, dk * 32 + h16)]);
                h8 kf1 = *(const h8*)(&lds[SWZI(32 + l31, dk * 32 + h16)]);
                S0 = MFMA32(kf0, qf[dk], S0);
                S1 = MFMA32(kf1, qf[dk], S1);
            }
            __builtin_amdgcn_s_setprio(0);

            // ---- causal mask (wave's final tile only) ----
            if (kb == kbw) {
#pragma unroll
                for (int r = 0; r < 16; ++r) {
                    int key = kb * 64 + (r & 3) + 8 * (r >> 2) + h4o;
                    if (key > qabs) S0[r] = -1e30f;
                    if (key + 32 > qabs) S1[r] = -1e30f;
                }
            }

            // ---- in-register online softmax (exp2 domain, T13 defer-rescale) ----
            float tr[16];
#pragma unroll
            for (int r = 0; r < 16; ++r) tr[r] = fmaxf(S0[r], S1[r]);
#pragma unroll
            for (int st = 8; st >= 1; st >>= 1)
#pragma unroll
                for (int r = 0; r < st; ++r) tr[r] = fmaxf(tr[r], tr[r + st]);
            float pm = fmaxf(tr[0], swap_half(tr[0]));
            if (!__all(pm - m <= 8.f)) {
                float mnew = fmaxf(m, pm);
                float scl = __builtin_amdgcn_exp2f(m - mnew);
                m = mnew;
                l *= scl;
#pragma unroll
                for (int r = 0; r < 16; ++r) { O0[r] *= scl; O1[r] *= scl; }
            }
#pragma unroll
            for (int r = 0; r < 16; ++r) {
                S0[r] = __builtin_amdgcn_exp2f(S0[r] - m);
                S1[r] = __builtin_amdgcn_exp2f(S1[r] - m);
            }
#pragma unroll
            for (int r = 0; r < 16; ++r) tr[r] = S0[r] + S1[r];
#pragma unroll
            for (int st = 8; st >= 1; st >>= 1)
#pragma unroll
                for (int r = 0; r < st; ++r) tr[r] += tr[r + st];
            l += tr[0] + swap_half(tr[0]);

            // ---- T12: pack P into PV B-frags (word exchange via shfl_xor 32) ----
            h8 pb[4];
#pragma unroll
            for (int kk = 0; kk < 4; ++kk) {
                const int bb = (kk & 1) * 8;
                unsigned W0, W1, W2, W3;
                if (kk < 2) {
                    W0 = __builtin_bit_cast(unsigned, __builtin_amdgcn_cvt_pkrtz(S0[bb + 0], S0[bb + 1]));
                    W1 = __builtin_bit_cast(unsigned, __builtin_amdgcn_cvt_pkrtz(S0[bb + 2], S0[bb + 3]));
                    W2 = __builtin_bit_cast(unsigned, __builtin_amdgcn_cvt_pkrtz(S0[bb + 4], S0[bb + 5]));
                    W3 = __builtin_bit_cast(unsigned, __builtin_amdgcn_cvt_pkrtz(S0[bb + 6], S0[bb + 7]));
                } else {
                    W0 = __builtin_bit_cast(unsigned, __builtin_amdgcn_cvt_pkrtz(S1[bb + 0], S1[bb + 1]));
                    W1 = __builtin_bit_cast(unsigned, __builtin_amdgcn_cvt_pkrtz(S1[bb + 2], S1[bb + 3]));
                    W2 = __builtin_bit_cast(unsigned, __builtin_amdgcn_cvt_pkrtz(S1[bb + 4], S1[bb + 5]));
                    W3 = __builtin_bit_cast(unsigned, __builtin_amdgcn_cvt_pkrtz(S1[bb + 6], S1[bb + 7]));
                }
                unsigned E0 = (unsigned)__shfl_xor((int)(hi ? W0 : W2), 32, 64);
                unsigned E1 = (unsigned)__shfl_xor((int)(hi ? W1 : W3), 32, 64);
                u4 wvv;
                wvv[0] = hi ? E0 : W0;
                wvv[1] = hi ? E1 : W1;
                wvv[2] = hi ? W2 : E0;
                wvv[3] = hi ? W3 : E1;
                pb[kk] = __builtin_bit_cast(h8, wvv);
            }

            // ---- PV swapped: O^T[d][q] += V^T-frag x P-frag ----
            __builtin_amdgcn_s_setprio(1);
#pragma unroll
            for (int kk = 0; kk < 4; ++kk) {
                h8 vf0 = *(const h8*)(&lds[4096 + SWZI(l31, kk * 32 + h16)]);
                h8 vf1 = *(const h8*)(&lds[4096 + SWZI(32 + l31, kk * 32 + h16)]);
                O0 = MFMA32(vf0, pb[kk], O0);
                O1 = MFMA32(vf1, pb[kk], O1);
            }
            __builtin_amdgcn_s_setprio(0);
        }

        __syncthreads();                   // all waves done reading tile kb
        if (pre) {
#pragma unroll
            for (int j = 0; j < 2; ++j) {
                int row = j * 32 + sr;
                *(h8*)(&lds[SWZI(row, scb)]) = kn[j];
                *(h8*)(&lds[4096 + SWZI(row, scb)]) = vn[j];
            }
            __syncthreads();               // tile kb+1 visible to all waves
        }
    }

    __syncthreads();                       // last-tile reads done everywhere; reuse LDS

    // ---- epilogue: O^T (lane=q, regs=d) -> swizzled LDS -> coalesced global ----
    {
        float inv = 1.0f / l;
        const int R = w * 32 + l31;        // block-local q row
#pragma unroll
        for (int rr = 0; rr < 4; ++rr) {
            h4 a, b;
#pragma unroll
            for (int q = 0; q < 4; ++q) {
                a[q] = (_Float16)(O0[rr * 4 + q] * inv);
                b[q] = (_Float16)(O1[rr * 4 + q] * inv);
            }
            *(h4*)(&lds[SWZI(R, rr * 16 + hi * 8)]) = a;
            *(h4*)(&lds[SWZI(R, 64 + rr * 16 + hi * 8)]) = b;
        }
    }
    __syncthreads();
    {
        const int b = bh >> 4, head = bh & 15;
        const int row = tid >> 1;          // 0..127
#pragma unroll
        for (int i = 0; i < 4; ++i) {
            int seg = (tid & 1) * 4 + i;
            h8 v = *(const h8*)(&lds[SWZI(row, seg * 16)]);
            *(h8*)(Yh + ((size_t)(b * 2048 + qt * 128 + row)) * 1024 + head * 64 + seg * 8) = v;
        }
    }
}

extern "C" void kernel_launch(void* const* d_in, const int* in_sizes, int n_in,
                              void* d_out, int out_size, void* d_ws, size_t ws_size,
                              hipStream_t stream) {
    const float* x  = (const float*)d_in[0];
    const float* Wa = (const float*)d_in[1];
    const float* ba = (const float*)d_in[2];
    const float* Wp = (const float*)d_in[3];
    const float* bp = (const float*)d_in[4];
    float* out = (float*)d_out;

    _Float16* ws = (_Float16*)d_ws;
    const size_t SZ_X = (size_t)8192 * 1024;
    const size_t SZ_WA = (size_t)3072 * 1024;
    const size_t SZ_WP = (size_t)1024 * 1024;
    const size_t SZ_H = (size_t)64 * 2048 * 64;
    _Float16* xh  = ws;
    _Float16* WaT = xh + SZ_X;
    _Float16* WpT = WaT + SZ_WA;
    _Float16* Qh  = WpT + SZ_WP;
    _Float16* Kh  = Qh + SZ_H;
    _Float16* Vth = Kh + SZ_H;    // V transposed: (bh, d, t)
    _Float16* Yh  = Vth + SZ_H;

    k_f32_to_f16<<<8192, 256, 0, stream>>>(x, xh, (int)(SZ_X / 4));
    k_transpose_f16<<<dim3(16, 48), 256, 0, stream>>>(Wa, WaT, 1024, 3072);
    k_transpose_f16<<<dim3(16, 16), 256, 0, stream>>>(Wp, WpT, 1024, 1024);
    k_gemm<0><<<dim3(64, 24), 256, 0, stream>>>(xh, WaT, ba, Qh, Kh, Vth, nullptr,
                                                8192, 3072, 1024);
    k_attn<<<1024, 256, 0, stream>>>(Qh, Kh, Vth, Yh);
    k_gemm<1><<<dim3(64, 8), 256, 0, stream>>>(Yh, WpT, bp, nullptr, nullptr, nullptr,
                                               out, 8192, 1024, 1024);
}